// Round 2
// baseline (2037.428 us; speedup 1.0000x reference)
//
#include <hip/hip_runtime.h>
#include <hip/hip_bf16.h>
#include <cstdint>
#include <cstddef>

#define NNODES 100000
#define DFEAT 128
#define KHOP 8
#define FAN1 1152        // D*(K+1)
#define HIDN 512
#define OUTD 32
#define NEDGE 1600000
#define BN_EPS 1e-5f
#define DEG_EPS 1e-8f

using short8 = __attribute__((ext_vector_type(8))) short;
using f32x4  = __attribute__((ext_vector_type(4))) float;

// ---------------- edge weights + degree + histogram ----------------
__global__ __launch_bounds__(256) void edge_kernel(
    const int* __restrict__ ei, const float* __restrict__ coor,
    const float* __restrict__ theta, const int* __restrict__ mm,
    float* __restrict__ deg, int* __restrict__ cnt)
{
    int e = blockIdx.x * 256 + threadIdx.x;
    if (e >= NEDGE) return;
    float tom = theta[0] / (float)mm[0];
    int r = ei[e], c = ei[NEDGE + e];
    float2 pr = *(const float2*)(coor + 2*(size_t)r);
    float2 pc = *(const float2*)(coor + 2*(size_t)c);
    float dx = pr.x - pc.x, dy = pr.y - pc.y;
    float w = expf(-(dx*dx + dy*dy) * tom);
    atomicAdd(&deg[r], w);
    atomicAdd(&cnt[r], 1);
}

// ---------------- single-block exclusive scan (row_ptr) ----------------
__global__ __launch_bounds__(1024) void scan_kernel(
    const int* __restrict__ cnt, int* __restrict__ row_ptr, int n)
{
    __shared__ int wsum[16];
    __shared__ int carry_s;
    int tid = threadIdx.x;
    int lane = tid & 63, wv = tid >> 6;
    if (tid == 0) { carry_s = 0; row_ptr[0] = 0; }
    for (int base = 0; base < n; base += 1024) {
        __syncthreads();
        int i = base + tid;
        int v = (i < n) ? cnt[i] : 0;
        #pragma unroll
        for (int off = 1; off < 64; off <<= 1) {
            int t = __shfl_up(v, off, 64);
            if (lane >= off) v += t;
        }
        if (lane == 63) wsum[wv] = v;
        __syncthreads();
        if (tid < 16) {
            int t = wsum[tid];
            #pragma unroll
            for (int off = 1; off < 16; off <<= 1) {
                int u = __shfl_up(t, off, 64);
                if (tid >= off) t += u;
            }
            wsum[tid] = t;
        }
        __syncthreads();
        int woff = (wv == 0) ? 0 : wsum[wv - 1];
        int carry = carry_s;
        int incl = v + woff + carry;
        if (i < n) row_ptr[i + 1] = incl;
        __syncthreads();
        if (tid == 0) carry_s = carry + wsum[15];
    }
}

// ---------------- CSR fill + norm (recompute w) ----------------
__global__ __launch_bounds__(256) void fill_kernel(
    const int* __restrict__ ei, const float* __restrict__ coor,
    const float* __restrict__ theta, const int* __restrict__ mm,
    const float* __restrict__ deg, const int* __restrict__ row_ptr,
    int* __restrict__ fill, int* __restrict__ cols, float* __restrict__ nrm)
{
    int e = blockIdx.x * 256 + threadIdx.x;
    if (e >= NEDGE) return;
    float tom = theta[0] / (float)mm[0];
    int r = ei[e], c = ei[NEDGE + e];
    float2 pr = *(const float2*)(coor + 2*(size_t)r);
    float2 pc = *(const float2*)(coor + 2*(size_t)c);
    float dx = pr.x - pc.x, dy = pr.y - pc.y;
    float w = expf(-(dx*dx + dy*dy) * tom);
    int pos = row_ptr[r] + atomicAdd(&fill[r], 1);
    cols[pos] = c;
    nrm[pos] = w / (deg[r] + DEG_EPS);
}

// ---------------- cast feature -> x slot0 (bf16, [N,128]) ----------------
__global__ __launch_bounds__(256) void cast_feat_kernel(
    const float* __restrict__ f, __hip_bfloat16* __restrict__ x0)
{
    int i = blockIdx.x * 256 + threadIdx.x;      // over N*64 float2 units
    int node = i >> 6, l2 = i & 63;
    if (node >= NNODES) return;
    float2 v = *(const float2*)(f + (size_t)node * DFEAT + l2 * 2);
    __hip_bfloat162 hb;
    hb.x = __float2bfloat16(v.x);
    hb.y = __float2bfloat16(v.y);
    *(__hip_bfloat162*)(x0 + (size_t)node * DFEAT + l2 * 2) = hb;
}

// ---------------- cast W1 -> bf16 ----------------
__global__ __launch_bounds__(256) void cast_w1_kernel(
    const float* __restrict__ w1, __hip_bfloat16* __restrict__ o)
{
    int i = blockIdx.x * 256 + threadIdx.x;
    if (i < HIDN * FAN1) o[i] = __float2bfloat16(w1[i]);
}

// ---------------- one propagation hop (bf16 in/out): wave per dst node ----
__global__ __launch_bounds__(256) void prop_kernel(
    const __hip_bfloat16* __restrict__ x, const int* __restrict__ row_ptr,
    const int* __restrict__ cols, const float* __restrict__ nrm,
    __hip_bfloat16* __restrict__ y)
{
    int gw = (blockIdx.x * 256 + threadIdx.x) >> 6;
    if (gw >= NNODES) return;
    int lane = threadIdx.x & 63;
    int beg = row_ptr[gw], end = row_ptr[gw + 1];
    float ax = 0.f, ay = 0.f;
    int e = beg;
    for (; e + 1 < end; e += 2) {
        int s0 = cols[e], s1 = cols[e + 1];
        float w0 = nrm[e], w1 = nrm[e + 1];
        uint32_t u0 = *(const uint32_t*)(x + (size_t)s0 * DFEAT + lane * 2);
        uint32_t u1 = *(const uint32_t*)(x + (size_t)s1 * DFEAT + lane * 2);
        float a0 = __uint_as_float(u0 << 16);
        float b0 = __uint_as_float(u0 & 0xffff0000u);
        float a1 = __uint_as_float(u1 << 16);
        float b1 = __uint_as_float(u1 & 0xffff0000u);
        ax += w0 * a0 + w1 * a1;
        ay += w0 * b0 + w1 * b1;
    }
    if (e < end) {
        int s0 = cols[e];
        float w0 = nrm[e];
        uint32_t u0 = *(const uint32_t*)(x + (size_t)s0 * DFEAT + lane * 2);
        ax += w0 * __uint_as_float(u0 << 16);
        ay += w0 * __uint_as_float(u0 & 0xffff0000u);
    }
    __hip_bfloat162 hb;
    hb.x = __float2bfloat16(ax);
    hb.y = __float2bfloat16(ay);
    *(__hip_bfloat162*)(y + (size_t)gw * DFEAT + lane * 2) = hb;
}

// ---------------- fc1 partial GEMM: [N,384]x[384,512] bf16 MFMA ----------
// mode 0: overwrite raw partial; 1: RMW raw; 2: RMW + bias + lrelu + stats
__global__ __launch_bounds__(256, 2) void fc1_kernel(
    const __hip_bfloat16* __restrict__ xb0, const __hip_bfloat16* __restrict__ xb1,
    const __hip_bfloat16* __restrict__ xb2, const __hip_bfloat16* __restrict__ w1,
    const float* __restrict__ b1, __hip_bfloat16* __restrict__ h1acc,
    float* __restrict__ gsum, float* __restrict__ gsq, int gsel, int mode)
{
    __shared__ __hip_bfloat16 As[64][48];
    __shared__ __hip_bfloat16 Bs[512][48];
    int m0 = blockIdx.x * 64;
    int tid = threadIdx.x, lane = tid & 63, wv = tid >> 6;
    int kbase = gsel * 384;

    f32x4 acc[4][8];
    #pragma unroll
    for (int i = 0; i < 4; ++i)
        #pragma unroll
        for (int j = 0; j < 8; ++j)
            acc[i][j] = (f32x4){0.f, 0.f, 0.f, 0.f};

    const __hip_bfloat16* xs[3] = {xb0, xb1, xb2};

    for (int kt = 0; kt < 12; ++kt) {
        __syncthreads();
        // stage A: row r = tid>>2, 8-elem chunk = tid&3, from x block kt>>2
        {
            const __hip_bfloat16* xp = xs[kt >> 2];
            int koff = (kt & 3) * 32;
            int r = tid >> 2, ch = tid & 3;
            int gm = m0 + r;
            short8 v = (short8){0,0,0,0,0,0,0,0};
            if (gm < NNODES) v = *(const short8*)(xp + (size_t)gm * DFEAT + koff + ch * 8);
            *(short8*)(&As[r][ch * 8]) = v;
        }
        // stage B: 512 rows of W1 slice, 8 passes
        {
            int kglob = kbase + kt * 32;
            #pragma unroll
            for (int p = 0; p < 8; ++p) {
                int nn = p * 64 + (tid >> 2), ch = tid & 3;
                short8 v = *(const short8*)(w1 + (size_t)nn * FAN1 + kglob + ch * 8);
                *(short8*)(&Bs[nn][ch * 8]) = v;
            }
        }
        __syncthreads();
        short8 afrag[4];
        #pragma unroll
        for (int i = 0; i < 4; ++i)
            afrag[i] = *(const short8*)(&As[i * 16 + (lane & 15)][(lane >> 4) * 8]);
        #pragma unroll
        for (int j = 0; j < 8; ++j) {
            int n = wv * 128 + j * 16 + (lane & 15);
            short8 bfrag = *(const short8*)(&Bs[n][(lane >> 4) * 8]);
            #pragma unroll
            for (int i = 0; i < 4; ++i)
                acc[i][j] = __builtin_amdgcn_mfma_f32_16x16x32_bf16(afrag[i], bfrag, acc[i][j], 0, 0, 0);
        }
    }

    // epilogue
    int rbase = (lane >> 4) * 4;
    #pragma unroll
    for (int j = 0; j < 8; ++j) {
        int col = wv * 128 + j * 16 + (lane & 15);
        float bias = (mode == 2) ? b1[col] : 0.f;
        float s_local = 0.f, q_local = 0.f;
        #pragma unroll
        for (int i = 0; i < 4; ++i) {
            #pragma unroll
            for (int r = 0; r < 4; ++r) {
                int gm = m0 + i * 16 + rbase + r;
                if (gm >= NNODES) continue;
                size_t idx = (size_t)gm * HIDN + col;
                float v = acc[i][j][r];
                if (mode != 0) v += __bfloat162float(h1acc[idx]);
                if (mode == 2) {
                    v += bias;
                    v = (v > 0.f) ? v : 0.2f * v;
                    s_local += v;
                    q_local += v * v;
                }
                h1acc[idx] = __float2bfloat16(v);
            }
        }
        if (mode == 2) {
            s_local += __shfl_xor(s_local, 16, 64);
            s_local += __shfl_xor(s_local, 32, 64);
            q_local += __shfl_xor(q_local, 16, 64);
            q_local += __shfl_xor(q_local, 32, 64);
            if ((lane >> 4) == 0) {
                atomicAdd(&gsum[col], s_local);
                atomicAdd(&gsq[col], q_local);
            }
        }
    }
}

// ---------------- BN finalize: fold into W2 + const vector ----------------
__global__ __launch_bounds__(512) void bn_finalize(
    const float* __restrict__ gsum, const float* __restrict__ gsq,
    const float* __restrict__ gamma, const float* __restrict__ beta,
    const float* __restrict__ w2, const float* __restrict__ b2,
    __hip_bfloat16* __restrict__ w2s, float* __restrict__ cvec)
{
    __shared__ float ts[HIDN];
    int tid = threadIdx.x;              // 512 threads
    float mu = gsum[tid] * (1.0f / NNODES);
    float var = gsq[tid] * (1.0f / NNODES) - mu * mu;
    float s = gamma[tid] * rsqrtf(var + BN_EPS);
    float t = beta[tid] - mu * s;
    ts[tid] = t;
    for (int o = 0; o < OUTD; ++o)
        w2s[o * HIDN + tid] = __float2bfloat16(w2[o * HIDN + tid] * s);
    __syncthreads();
    int lane = tid & 63, wv = tid >> 6; // 8 waves
    for (int o = wv; o < OUTD; o += 8) {
        float p = 0.f;
        for (int j = lane; j < HIDN; j += 64) p += ts[j] * w2[o * HIDN + j];
        #pragma unroll
        for (int off = 32; off; off >>= 1) p += __shfl_xor(p, off, 64);
        if (lane == 0) cvec[o] = p + b2[o];
    }
}

// ---------------- fc2: [N,512]x[512,32] bf16 MFMA ----------------
__global__ __launch_bounds__(256) void fc2_kernel(
    const __hip_bfloat16* __restrict__ h1, const __hip_bfloat16* __restrict__ w2s,
    const float* __restrict__ cvec, float* __restrict__ out)
{
    int gw = (blockIdx.x * 256 + threadIdx.x) >> 6;
    if (gw >= NNODES / 16) return;
    int lane = threadIdx.x & 63;
    int m0 = gw * 16;
    f32x4 acc[2];
    acc[0] = (f32x4){0.f, 0.f, 0.f, 0.f};
    acc[1] = (f32x4){0.f, 0.f, 0.f, 0.f};
    #pragma unroll
    for (int kt = 0; kt < HIDN / 32; ++kt) {
        int k0 = kt * 32;
        short8 a = *(const short8*)(h1 + (size_t)(m0 + (lane & 15)) * HIDN + k0 + (lane >> 4) * 8);
        #pragma unroll
        for (int j = 0; j < 2; ++j) {
            short8 b = *(const short8*)(w2s + (size_t)(j * 16 + (lane & 15)) * HIDN + k0 + (lane >> 4) * 8);
            acc[j] = __builtin_amdgcn_mfma_f32_16x16x32_bf16(a, b, acc[j], 0, 0, 0);
        }
    }
    #pragma unroll
    for (int j = 0; j < 2; ++j) {
        int col = j * 16 + (lane & 15);
        float cadd = cvec[col];
        #pragma unroll
        for (int r = 0; r < 4; ++r) {
            int row = m0 + (lane >> 4) * 4 + r;
            out[(size_t)row * OUTD + col] = acc[j][r] + cadd;
        }
    }
}

// ---------------- host ----------------
static inline char* align_up(char* p, size_t a) {
    return (char*)(((uintptr_t)p + a - 1) & ~(a - 1));
}

extern "C" void kernel_launch(void* const* d_in, const int* in_sizes, int n_in,
                              void* d_out, int out_size, void* d_ws, size_t ws_size,
                              hipStream_t stream)
{
    const float* feature = (const float*)d_in[0];
    const float* coor    = (const float*)d_in[1];
    const float* theta   = (const float*)d_in[2];
    const float* W1      = (const float*)d_in[3];
    const float* b1      = (const float*)d_in[4];
    const float* gamma   = (const float*)d_in[5];
    const float* beta    = (const float*)d_in[6];
    const float* W2      = (const float*)d_in[7];
    const float* b2      = (const float*)d_in[8];
    const int*   ei      = (const int*)d_in[9];
    const int*   mm      = (const int*)d_in[10];
    float* out = (float*)d_out;

    char* p = (char*)d_ws;
    auto take = [&](size_t bytes) { char* q = align_up(p, 256); p = q + bytes; return q; };

    float* deg     = (float*)take((size_t)NNODES * 4);
    int*   cnt     = (int*)  take((size_t)NNODES * 4);
    int*   fillc   = (int*)  take((size_t)NNODES * 4);
    int*   row_ptr = (int*)  take((size_t)(NNODES + 1) * 4);
    int*   colsb   = (int*)  take((size_t)NEDGE * 4);
    float* nrm     = (float*)take((size_t)NEDGE * 4);
    __hip_bfloat16* xs0 = (__hip_bfloat16*)take((size_t)NNODES * DFEAT * 2);
    __hip_bfloat16* xs1 = (__hip_bfloat16*)take((size_t)NNODES * DFEAT * 2);
    __hip_bfloat16* xs2 = (__hip_bfloat16*)take((size_t)NNODES * DFEAT * 2);
    __hip_bfloat16* h1acc = (__hip_bfloat16*)take((size_t)NNODES * HIDN * 2);
    __hip_bfloat16* w1b = (__hip_bfloat16*)take((size_t)HIDN * FAN1 * 2);
    __hip_bfloat16* w2s = (__hip_bfloat16*)take((size_t)OUTD * HIDN * 2);
    float* gsum = (float*)take(HIDN * 4);
    float* gsq  = (float*)take(HIDN * 4);
    float* cvec = (float*)take(OUTD * 4);
    (void)ws_size; (void)in_sizes; (void)n_in; (void)out_size;

    hipMemsetAsync(deg,   0, (size_t)NNODES * 4, stream);
    hipMemsetAsync(cnt,   0, (size_t)NNODES * 4, stream);
    hipMemsetAsync(fillc, 0, (size_t)NNODES * 4, stream);
    hipMemsetAsync(gsum,  0, HIDN * 4, stream);
    hipMemsetAsync(gsq,   0, HIDN * 4, stream);

    int eb = (NEDGE + 255) / 256;
    edge_kernel<<<eb, 256, 0, stream>>>(ei, coor, theta, mm, deg, cnt);
    scan_kernel<<<1, 1024, 0, stream>>>(cnt, row_ptr, NNODES);
    fill_kernel<<<eb, 256, 0, stream>>>(ei, coor, theta, mm, deg, row_ptr, fillc, colsb, nrm);

    cast_feat_kernel<<<(NNODES * 64) / 256, 256, 0, stream>>>(feature, xs0);
    cast_w1_kernel<<<(HIDN * FAN1 + 255) / 256, 256, 0, stream>>>(W1, w1b);

    int pb = (NNODES * 64) / 256;
    int fb = (NNODES + 63) / 64;
    __hip_bfloat16* slot[3] = {xs0, xs1, xs2};

    // blocks 0..8 live in slots cyclically; GEMM after every 3rd block ready
    // P1: s0->s1, P2: s1->s2, G0(s0,s1,s2), P3: s2->s0, P4: s0->s1, P5: s1->s2,
    // G1, P6: s2->s0, P7: s0->s1, P8: s1->s2, G2
    int cur = 0; // slot holding newest block
    int gcount = 0;
    for (int k = 1; k <= KHOP; ++k) {
        int nxt = k % 3;
        prop_kernel<<<pb, 256, 0, stream>>>(slot[cur], row_ptr, colsb, nrm, slot[nxt]);
        cur = nxt;
        if (k % 3 == 2) { // blocks (k-2,k-1,k) = slots (0,1,2) ready
            int mode = (gcount == 0) ? 0 : 1;
            fc1_kernel<<<fb, 256, 0, stream>>>(xs0, xs1, xs2, w1b, b1, h1acc,
                                               gsum, gsq, gcount, mode);
            ++gcount;
        }
    }
    // last triple (blocks 6,7,8) in slots (0,1,2)
    fc1_kernel<<<fb, 256, 0, stream>>>(xs0, xs1, xs2, w1b, b1, h1acc,
                                       gsum, gsq, gcount, 2);

    bn_finalize<<<1, 512, 0, stream>>>(gsum, gsq, gamma, beta, W2, b2, w2s, cvec);
    fc2_kernel<<<(NNODES / 16 * 64 + 255) / 256, 256, 0, stream>>>(h1acc, w2s, cvec, out);
}

// Round 3
// 1351.044 us; speedup vs baseline: 1.5080x; 1.5080x over previous
//
#include <hip/hip_runtime.h>
#include <hip/hip_bf16.h>
#include <cstdint>
#include <cstddef>

#define NNODES 100000
#define DFEAT 128
#define KHOP 8
#define FAN1 1152        // D*(K+1)
#define HIDN 512
#define OUTD 32
#define NEDGE 1600000
#define BN_EPS 1e-5f
#define DEG_EPS 1e-8f

using short8 = __attribute__((ext_vector_type(8))) short;
using f32x4  = __attribute__((ext_vector_type(4))) float;

__device__ __forceinline__ float bf16lo(uint32_t u) { return __uint_as_float(u << 16); }
__device__ __forceinline__ float bf16hi(uint32_t u) { return __uint_as_float(u & 0xffff0000u); }
__device__ __forceinline__ float bf16s(short x) {
    return __uint_as_float(((uint32_t)(uint16_t)x) << 16);
}

__device__ __forceinline__ void gload16(const void* g, void* l) {
    __builtin_amdgcn_global_load_lds(
        (const __attribute__((address_space(1))) uint32_t*)g,
        (__attribute__((address_space(3))) uint32_t*)l, 16, 0, 0);
}

// ---------------- edge weights + degree + histogram ----------------
__global__ __launch_bounds__(256) void edge_kernel(
    const int* __restrict__ ei, const float* __restrict__ coor,
    const float* __restrict__ theta, const int* __restrict__ mm,
    float* __restrict__ deg, int* __restrict__ cnt)
{
    int e = blockIdx.x * 256 + threadIdx.x;
    if (e >= NEDGE) return;
    float tom = theta[0] / (float)mm[0];
    int r = ei[e], c = ei[NEDGE + e];
    float2 pr = *(const float2*)(coor + 2*(size_t)r);
    float2 pc = *(const float2*)(coor + 2*(size_t)c);
    float dx = pr.x - pc.x, dy = pr.y - pc.y;
    float w = expf(-(dx*dx + dy*dy) * tom);
    atomicAdd(&deg[r], w);
    atomicAdd(&cnt[r], 1);
}

// ---------------- single-block exclusive scan (row_ptr) ----------------
__global__ __launch_bounds__(1024) void scan_kernel(
    const int* __restrict__ cnt, int* __restrict__ row_ptr, int n)
{
    __shared__ int wsum[16];
    __shared__ int carry_s;
    int tid = threadIdx.x;
    int lane = tid & 63, wv = tid >> 6;
    if (tid == 0) { carry_s = 0; row_ptr[0] = 0; }
    for (int base = 0; base < n; base += 1024) {
        __syncthreads();
        int i = base + tid;
        int v = (i < n) ? cnt[i] : 0;
        #pragma unroll
        for (int off = 1; off < 64; off <<= 1) {
            int t = __shfl_up(v, off, 64);
            if (lane >= off) v += t;
        }
        if (lane == 63) wsum[wv] = v;
        __syncthreads();
        if (tid < 16) {
            int t = wsum[tid];
            #pragma unroll
            for (int off = 1; off < 16; off <<= 1) {
                int u = __shfl_up(t, off, 64);
                if (tid >= off) t += u;
            }
            wsum[tid] = t;
        }
        __syncthreads();
        int woff = (wv == 0) ? 0 : wsum[wv - 1];
        int carry = carry_s;
        int incl = v + woff + carry;
        if (i < n) row_ptr[i + 1] = incl;
        __syncthreads();
        if (tid == 0) carry_s = carry + wsum[15];
    }
}

// ---------------- CSR fill + norm (recompute w) ----------------
__global__ __launch_bounds__(256) void fill_kernel(
    const int* __restrict__ ei, const float* __restrict__ coor,
    const float* __restrict__ theta, const int* __restrict__ mm,
    const float* __restrict__ deg, const int* __restrict__ row_ptr,
    int* __restrict__ fill, int* __restrict__ cols, float* __restrict__ nrm)
{
    int e = blockIdx.x * 256 + threadIdx.x;
    if (e >= NEDGE) return;
    float tom = theta[0] / (float)mm[0];
    int r = ei[e], c = ei[NEDGE + e];
    float2 pr = *(const float2*)(coor + 2*(size_t)r);
    float2 pc = *(const float2*)(coor + 2*(size_t)c);
    float dx = pr.x - pc.x, dy = pr.y - pc.y;
    float w = expf(-(dx*dx + dy*dy) * tom);
    int pos = row_ptr[r] + atomicAdd(&fill[r], 1);
    cols[pos] = c;
    nrm[pos] = w / (deg[r] + DEG_EPS);
}

// ---------------- cast feature -> x slot0 (bf16, [N,128]) ----------------
__global__ __launch_bounds__(256) void cast_feat_kernel(
    const float* __restrict__ f, __hip_bfloat16* __restrict__ x0)
{
    int i = blockIdx.x * 256 + threadIdx.x;      // over N*64 float2 units
    int node = i >> 6, l2 = i & 63;
    if (node >= NNODES) return;
    float2 v = *(const float2*)(f + (size_t)node * DFEAT + l2 * 2);
    __hip_bfloat162 hb;
    hb.x = __float2bfloat16(v.x);
    hb.y = __float2bfloat16(v.y);
    *(__hip_bfloat162*)(x0 + (size_t)node * DFEAT + l2 * 2) = hb;
}

// ---------------- cast W1 -> bf16 ----------------
__global__ __launch_bounds__(256) void cast_w1_kernel(
    const float* __restrict__ w1, __hip_bfloat16* __restrict__ o)
{
    int i = blockIdx.x * 256 + threadIdx.x;
    if (i < HIDN * FAN1) o[i] = __float2bfloat16(w1[i]);
}

// ---------------- one propagation hop (bf16 in/out): wave per dst node ----
__global__ __launch_bounds__(256) void prop_kernel(
    const __hip_bfloat16* __restrict__ x, const int* __restrict__ row_ptr,
    const int* __restrict__ cols, const float* __restrict__ nrm,
    __hip_bfloat16* __restrict__ y)
{
    int gw = (blockIdx.x * 256 + threadIdx.x) >> 6;
    if (gw >= NNODES) return;
    int lane = threadIdx.x & 63;
    int beg = row_ptr[gw], end = row_ptr[gw + 1];
    float ax = 0.f, ay = 0.f, bx = 0.f, by = 0.f;
    int e = beg;
    for (; e + 3 < end; e += 4) {
        int s0 = cols[e], s1 = cols[e + 1], s2 = cols[e + 2], s3 = cols[e + 3];
        float w0 = nrm[e], w1 = nrm[e + 1], w2 = nrm[e + 2], w3 = nrm[e + 3];
        uint32_t u0 = *(const uint32_t*)(x + (size_t)s0 * DFEAT + lane * 2);
        uint32_t u1 = *(const uint32_t*)(x + (size_t)s1 * DFEAT + lane * 2);
        uint32_t u2 = *(const uint32_t*)(x + (size_t)s2 * DFEAT + lane * 2);
        uint32_t u3 = *(const uint32_t*)(x + (size_t)s3 * DFEAT + lane * 2);
        ax += w0 * bf16lo(u0); ay += w0 * bf16hi(u0);
        bx += w1 * bf16lo(u1); by += w1 * bf16hi(u1);
        ax += w2 * bf16lo(u2); ay += w2 * bf16hi(u2);
        bx += w3 * bf16lo(u3); by += w3 * bf16hi(u3);
    }
    for (; e < end; ++e) {
        int s0 = cols[e];
        float w0 = nrm[e];
        uint32_t u0 = *(const uint32_t*)(x + (size_t)s0 * DFEAT + lane * 2);
        ax += w0 * bf16lo(u0);
        ay += w0 * bf16hi(u0);
    }
    ax += bx; ay += by;
    __hip_bfloat162 hb;
    hb.x = __float2bfloat16(ax);
    hb.y = __float2bfloat16(ay);
    *(__hip_bfloat162*)(y + (size_t)gw * DFEAT + lane * 2) = hb;
}

// ---------------- fc1 partial GEMM: m97-style 128x128 tile, BK=32 --------
// grid (782, 4); K=384 per launch (3 x-blocks of 128)
// mode 0: overwrite raw partial; 1: RMW; 2: RMW + bias + lrelu + stats
__global__ __launch_bounds__(256) void fc1_kernel(
    const __hip_bfloat16* __restrict__ xb0, const __hip_bfloat16* __restrict__ xb1,
    const __hip_bfloat16* __restrict__ xb2, const __hip_bfloat16* __restrict__ w1,
    const float* __restrict__ b1, __hip_bfloat16* __restrict__ h1acc,
    float* __restrict__ gsum, float* __restrict__ gsq, int gsel, int mode)
{
    __shared__ char smem[33792];   // As 8K | Bs 8K ; epilogue: tile 32K + stats 1K
    char* As = smem;
    char* Bs = smem + 8192;

    int m0 = blockIdx.x * 128;
    int n0 = blockIdx.y * 128;
    int tid = threadIdx.x, lane = tid & 63, wv = tid >> 6;
    int wr = wv >> 1, wc = wv & 1;          // wave quadrant (2x2 of 64x64)
    int kbase = gsel * 384;

    f32x4 acc[4][4];
    #pragma unroll
    for (int i = 0; i < 4; ++i)
        #pragma unroll
        for (int j = 0; j < 4; ++j)
            acc[i][j] = (f32x4){0.f, 0.f, 0.f, 0.f};

    const __hip_bfloat16* xs[3] = {xb0, xb1, xb2};

    for (int kt = 0; kt < 12; ++kt) {
        const __hip_bfloat16* xp = xs[kt >> 2];
        int koff = (kt & 3) * 32;
        int kglob = kbase + kt * 32;
        __syncthreads();
        // stage A (128x32) and B (128x32) via global_load_lds, 16B/lane
        #pragma unroll
        for (int l = 0; l < 2; ++l) {
            int u = l * 256 + wv * 64 + lane;
            int row = u >> 2, q = u & 3;
            gload16(xp + (size_t)(m0 + row) * DFEAT + koff + q * 8,
                    As + (l * 256 + wv * 64) * 16);
            gload16(w1 + (size_t)(n0 + row) * FAN1 + kglob + q * 8,
                    Bs + (l * 256 + wv * 64) * 16);
        }
        __syncthreads();
        short8 af[4], bf[4];
        #pragma unroll
        for (int i = 0; i < 4; ++i)
            af[i] = *(const short8*)(As + (wr * 64 + i * 16 + (lane & 15)) * 64 + (lane >> 4) * 16);
        #pragma unroll
        for (int j = 0; j < 4; ++j)
            bf[j] = *(const short8*)(Bs + (wc * 64 + j * 16 + (lane & 15)) * 64 + (lane >> 4) * 16);
        #pragma unroll
        for (int j = 0; j < 4; ++j)
            #pragma unroll
            for (int i = 0; i < 4; ++i)
                acc[i][j] = __builtin_amdgcn_mfma_f32_16x16x32_bf16(af[i], bf[j], acc[i][j], 0, 0, 0);
    }

    // ---- epilogue: stage bf16 tile in LDS, coalesced RMW of h1acc ----
    __syncthreads();
    __hip_bfloat16* tile = (__hip_bfloat16*)smem;      // [128][128]
    float* lsum = (float*)(smem + 32768);              // [128]
    float* lsq  = lsum + 128;
    if (mode == 2 && tid < 128) { lsum[tid] = 0.f; lsq[tid] = 0.f; }
    #pragma unroll
    for (int i = 0; i < 4; ++i) {
        #pragma unroll
        for (int j = 0; j < 4; ++j) {
            int col = wc * 64 + j * 16 + (lane & 15);
            #pragma unroll
            for (int r = 0; r < 4; ++r) {
                int row = wr * 64 + i * 16 + (lane >> 4) * 4 + r;
                tile[row * 128 + col] = __float2bfloat16(acc[i][j][r]);
            }
        }
    }
    __syncthreads();

    int cu = tid & 15, tr = tid >> 4;
    float bias[8];
    float s[8], q[8];
    #pragma unroll
    for (int e = 0; e < 8; ++e) { s[e] = 0.f; q[e] = 0.f; }
    if (mode == 2) {
        #pragma unroll
        for (int e = 0; e < 8; ++e) bias[e] = b1[n0 + cu * 8 + e];
    }
    for (int p = 0; p < 8; ++p) {
        int row = p * 16 + tr;
        int gm = m0 + row;
        if (gm >= NNODES) continue;
        short8 fresh = *(const short8*)(tile + row * 128 + cu * 8);
        size_t gidx = (size_t)gm * HIDN + n0 + cu * 8;
        float v[8];
        #pragma unroll
        for (int e = 0; e < 8; ++e) v[e] = bf16s(fresh[e]);
        if (mode != 0) {
            short8 prev = *(const short8*)(h1acc + gidx);
            #pragma unroll
            for (int e = 0; e < 8; ++e) v[e] += bf16s(prev[e]);
        }
        if (mode == 2) {
            #pragma unroll
            for (int e = 0; e < 8; ++e) {
                float t = v[e] + bias[e];
                t = (t > 0.f) ? t : 0.2f * t;
                v[e] = t;
                s[e] += t;
                q[e] += t * t;
            }
        }
        short8 outv;
        #pragma unroll
        for (int e = 0; e < 8; ++e) outv[e] = (short)__bfloat16_as_ushort(__float2bfloat16(v[e]));
        *(short8*)(h1acc + gidx) = outv;
    }
    if (mode == 2) {
        #pragma unroll
        for (int e = 0; e < 8; ++e) {
            atomicAdd(&lsum[cu * 8 + e], s[e]);
            atomicAdd(&lsq[cu * 8 + e], q[e]);
        }
        __syncthreads();
        if (tid < 128) {
            atomicAdd(&gsum[n0 + tid], lsum[tid]);
            atomicAdd(&gsq[n0 + tid], lsq[tid]);
        }
    }
}

// ---------------- BN finalize: fold into W2 + const vector ----------------
__global__ __launch_bounds__(512) void bn_finalize(
    const float* __restrict__ gsum, const float* __restrict__ gsq,
    const float* __restrict__ gamma, const float* __restrict__ beta,
    const float* __restrict__ w2, const float* __restrict__ b2,
    __hip_bfloat16* __restrict__ w2s, float* __restrict__ cvec)
{
    __shared__ float ts[HIDN];
    int tid = threadIdx.x;              // 512 threads
    float mu = gsum[tid] * (1.0f / NNODES);
    float var = gsq[tid] * (1.0f / NNODES) - mu * mu;
    float s = gamma[tid] * rsqrtf(var + BN_EPS);
    float t = beta[tid] - mu * s;
    ts[tid] = t;
    for (int o = 0; o < OUTD; ++o)
        w2s[o * HIDN + tid] = __float2bfloat16(w2[o * HIDN + tid] * s);
    __syncthreads();
    int lane = tid & 63, wv = tid >> 6; // 8 waves
    for (int o = wv; o < OUTD; o += 8) {
        float p = 0.f;
        for (int j = lane; j < HIDN; j += 64) p += ts[j] * w2[o * HIDN + j];
        #pragma unroll
        for (int off = 32; off; off >>= 1) p += __shfl_xor(p, off, 64);
        if (lane == 0) cvec[o] = p + b2[o];
    }
}

// ---------------- fc2: [N,512]x[512,32] bf16 MFMA ----------------
__global__ __launch_bounds__(256) void fc2_kernel(
    const __hip_bfloat16* __restrict__ h1, const __hip_bfloat16* __restrict__ w2s,
    const float* __restrict__ cvec, float* __restrict__ out)
{
    int gw = (blockIdx.x * 256 + threadIdx.x) >> 6;
    if (gw >= NNODES / 16) return;
    int lane = threadIdx.x & 63;
    int m0 = gw * 16;
    f32x4 acc[2];
    acc[0] = (f32x4){0.f, 0.f, 0.f, 0.f};
    acc[1] = (f32x4){0.f, 0.f, 0.f, 0.f};
    #pragma unroll
    for (int kt = 0; kt < HIDN / 32; ++kt) {
        int k0 = kt * 32;
        short8 a = *(const short8*)(h1 + (size_t)(m0 + (lane & 15)) * HIDN + k0 + (lane >> 4) * 8);
        #pragma unroll
        for (int j = 0; j < 2; ++j) {
            short8 b = *(const short8*)(w2s + (size_t)(j * 16 + (lane & 15)) * HIDN + k0 + (lane >> 4) * 8);
            acc[j] = __builtin_amdgcn_mfma_f32_16x16x32_bf16(a, b, acc[j], 0, 0, 0);
        }
    }
    #pragma unroll
    for (int j = 0; j < 2; ++j) {
        int col = j * 16 + (lane & 15);
        float cadd = cvec[col];
        #pragma unroll
        for (int r = 0; r < 4; ++r) {
            int row = m0 + (lane >> 4) * 4 + r;
            out[(size_t)row * OUTD + col] = acc[j][r] + cadd;
        }
    }
}

// ---------------- host ----------------
static inline char* align_up(char* p, size_t a) {
    return (char*)(((uintptr_t)p + a - 1) & ~(a - 1));
}

extern "C" void kernel_launch(void* const* d_in, const int* in_sizes, int n_in,
                              void* d_out, int out_size, void* d_ws, size_t ws_size,
                              hipStream_t stream)
{
    const float* feature = (const float*)d_in[0];
    const float* coor    = (const float*)d_in[1];
    const float* theta   = (const float*)d_in[2];
    const float* W1      = (const float*)d_in[3];
    const float* b1      = (const float*)d_in[4];
    const float* gamma   = (const float*)d_in[5];
    const float* beta    = (const float*)d_in[6];
    const float* W2      = (const float*)d_in[7];
    const float* b2      = (const float*)d_in[8];
    const int*   ei      = (const int*)d_in[9];
    const int*   mm      = (const int*)d_in[10];
    float* out = (float*)d_out;

    char* p = (char*)d_ws;
    auto take = [&](size_t bytes) { char* q = align_up(p, 256); p = q + bytes; return q; };

    float* deg     = (float*)take((size_t)NNODES * 4);
    int*   cnt     = (int*)  take((size_t)NNODES * 4);
    int*   fillc   = (int*)  take((size_t)NNODES * 4);
    int*   row_ptr = (int*)  take((size_t)(NNODES + 1) * 4);
    int*   colsb   = (int*)  take((size_t)NEDGE * 4);
    float* nrm     = (float*)take((size_t)NEDGE * 4);
    __hip_bfloat16* xs0 = (__hip_bfloat16*)take((size_t)NNODES * DFEAT * 2);
    __hip_bfloat16* xs1 = (__hip_bfloat16*)take((size_t)NNODES * DFEAT * 2);
    __hip_bfloat16* xs2 = (__hip_bfloat16*)take((size_t)NNODES * DFEAT * 2);
    __hip_bfloat16* h1acc = (__hip_bfloat16*)take((size_t)NNODES * HIDN * 2);
    __hip_bfloat16* w1b = (__hip_bfloat16*)take((size_t)HIDN * FAN1 * 2);
    __hip_bfloat16* w2s = (__hip_bfloat16*)take((size_t)OUTD * HIDN * 2);
    float* gsum = (float*)take(HIDN * 4);
    float* gsq  = (float*)take(HIDN * 4);
    float* cvec = (float*)take(OUTD * 4);
    (void)ws_size; (void)in_sizes; (void)n_in; (void)out_size;

    hipMemsetAsync(deg,   0, (size_t)NNODES * 4, stream);
    hipMemsetAsync(cnt,   0, (size_t)NNODES * 4, stream);
    hipMemsetAsync(fillc, 0, (size_t)NNODES * 4, stream);
    hipMemsetAsync(gsum,  0, HIDN * 4, stream);
    hipMemsetAsync(gsq,   0, HIDN * 4, stream);

    int eb = (NEDGE + 255) / 256;
    edge_kernel<<<eb, 256, 0, stream>>>(ei, coor, theta, mm, deg, cnt);
    scan_kernel<<<1, 1024, 0, stream>>>(cnt, row_ptr, NNODES);
    fill_kernel<<<eb, 256, 0, stream>>>(ei, coor, theta, mm, deg, row_ptr, fillc, colsb, nrm);

    cast_feat_kernel<<<(NNODES * 64) / 256, 256, 0, stream>>>(feature, xs0);
    cast_w1_kernel<<<(HIDN * FAN1 + 255) / 256, 256, 0, stream>>>(W1, w1b);

    int pb = (NNODES * 64) / 256;
    dim3 fgrid((NNODES + 127) / 128, 4);
    __hip_bfloat16* slot[3] = {xs0, xs1, xs2};

    // P1: s0->s1, P2: s1->s2, G0(s0,s1,s2), P3: s2->s0, P4, P5, G1, P6..P8, G2
    int cur = 0;
    int gcount = 0;
    for (int k = 1; k <= KHOP; ++k) {
        int nxt = k % 3;
        prop_kernel<<<pb, 256, 0, stream>>>(slot[cur], row_ptr, colsb, nrm, slot[nxt]);
        cur = nxt;
        if (k % 3 == 2) {
            int mode = (gcount == 0) ? 0 : 1;
            fc1_kernel<<<fgrid, 256, 0, stream>>>(xs0, xs1, xs2, w1b, b1, h1acc,
                                                  gsum, gsq, gcount, mode);
            ++gcount;
        }
    }
    fc1_kernel<<<fgrid, 256, 0, stream>>>(xs0, xs1, xs2, w1b, b1, h1acc,
                                          gsum, gsq, gcount, 2);

    bn_finalize<<<1, 512, 0, stream>>>(gsum, gsq, gamma, beta, W2, b2, w2s, cvec);
    fc2_kernel<<<(NNODES / 16 * 64 + 255) / 256, 256, 0, stream>>>(h1acc, w2s, cvec, out);
}

// Round 4
// 1276.193 us; speedup vs baseline: 1.5965x; 1.0587x over previous
//
#include <hip/hip_runtime.h>
#include <hip/hip_bf16.h>
#include <cstdint>
#include <cstddef>

#define NNODES 100000
#define DFEAT 128
#define KHOP 8
#define FAN1 1152        // D*(K+1)
#define HIDN 512
#define OUTD 32
#define NEDGE 1600000
#define BN_EPS 1e-5f
#define DEG_EPS 1e-8f

using short8 = __attribute__((ext_vector_type(8))) short;
using f32x4  = __attribute__((ext_vector_type(4))) float;

__device__ __forceinline__ float bf16lo(uint32_t u) { return __uint_as_float(u << 16); }
__device__ __forceinline__ float bf16hi(uint32_t u) { return __uint_as_float(u & 0xffff0000u); }
__device__ __forceinline__ float bf16s(short x) {
    return __uint_as_float(((uint32_t)(uint16_t)x) << 16);
}
__device__ __forceinline__ uint32_t packbf(float a, float b) {
    uint32_t lo = __bfloat16_as_ushort(__float2bfloat16(a));
    uint32_t hi = __bfloat16_as_ushort(__float2bfloat16(b));
    return lo | (hi << 16);
}

__device__ __forceinline__ void gload16(const void* g, void* l) {
    __builtin_amdgcn_global_load_lds(
        (const __attribute__((address_space(1))) uint32_t*)g,
        (__attribute__((address_space(3))) uint32_t*)l, 16, 0, 0);
}

// ---------------- edge weights + degree + histogram ----------------
__global__ __launch_bounds__(256) void edge_kernel(
    const int* __restrict__ ei, const float* __restrict__ coor,
    const float* __restrict__ theta, const int* __restrict__ mm,
    float* __restrict__ deg, int* __restrict__ cnt)
{
    int e = blockIdx.x * 256 + threadIdx.x;
    if (e >= NEDGE) return;
    float tom = theta[0] / (float)mm[0];
    int r = ei[e], c = ei[NEDGE + e];
    float2 pr = *(const float2*)(coor + 2*(size_t)r);
    float2 pc = *(const float2*)(coor + 2*(size_t)c);
    float dx = pr.x - pc.x, dy = pr.y - pc.y;
    float w = expf(-(dx*dx + dy*dy) * tom);
    atomicAdd(&deg[r], w);
    atomicAdd(&cnt[r], 1);
}

// ---------------- single-block exclusive scan (row_ptr) ----------------
__global__ __launch_bounds__(1024) void scan_kernel(
    const int* __restrict__ cnt, int* __restrict__ row_ptr, int n)
{
    __shared__ int wsum[16];
    __shared__ int carry_s;
    int tid = threadIdx.x;
    int lane = tid & 63, wv = tid >> 6;
    if (tid == 0) { carry_s = 0; row_ptr[0] = 0; }
    for (int base = 0; base < n; base += 1024) {
        __syncthreads();
        int i = base + tid;
        int v = (i < n) ? cnt[i] : 0;
        #pragma unroll
        for (int off = 1; off < 64; off <<= 1) {
            int t = __shfl_up(v, off, 64);
            if (lane >= off) v += t;
        }
        if (lane == 63) wsum[wv] = v;
        __syncthreads();
        if (tid < 16) {
            int t = wsum[tid];
            #pragma unroll
            for (int off = 1; off < 16; off <<= 1) {
                int u = __shfl_up(t, off, 64);
                if (tid >= off) t += u;
            }
            wsum[tid] = t;
        }
        __syncthreads();
        int woff = (wv == 0) ? 0 : wsum[wv - 1];
        int carry = carry_s;
        int incl = v + woff + carry;
        if (i < n) row_ptr[i + 1] = incl;
        __syncthreads();
        if (tid == 0) carry_s = carry + wsum[15];
    }
}

// ---------------- CSR fill + norm (recompute w) ----------------
__global__ __launch_bounds__(256) void fill_kernel(
    const int* __restrict__ ei, const float* __restrict__ coor,
    const float* __restrict__ theta, const int* __restrict__ mm,
    const float* __restrict__ deg, const int* __restrict__ row_ptr,
    int* __restrict__ fill, int* __restrict__ cols, float* __restrict__ nrm)
{
    int e = blockIdx.x * 256 + threadIdx.x;
    if (e >= NEDGE) return;
    float tom = theta[0] / (float)mm[0];
    int r = ei[e], c = ei[NEDGE + e];
    float2 pr = *(const float2*)(coor + 2*(size_t)r);
    float2 pc = *(const float2*)(coor + 2*(size_t)c);
    float dx = pr.x - pc.x, dy = pr.y - pc.y;
    float w = expf(-(dx*dx + dy*dy) * tom);
    int pos = row_ptr[r] + atomicAdd(&fill[r], 1);
    cols[pos] = c;
    nrm[pos] = w / (deg[r] + DEG_EPS);
}

// ---------------- cast feature -> bf16 x (stride param) ----------------
__global__ __launch_bounds__(256) void cast_feat_kernel(
    const float* __restrict__ f, __hip_bfloat16* __restrict__ x0, int stride)
{
    int i = blockIdx.x * 256 + threadIdx.x;      // over N*64 float2 units
    int node = i >> 6, l2 = i & 63;
    if (node >= NNODES) return;
    float2 v = *(const float2*)(f + (size_t)node * DFEAT + l2 * 2);
    __hip_bfloat162 hb;
    hb.x = __float2bfloat16(v.x);
    hb.y = __float2bfloat16(v.y);
    *(__hip_bfloat162*)(x0 + (size_t)node * stride + l2 * 2) = hb;
}

// ---------------- cast W1 -> bf16 ----------------
__global__ __launch_bounds__(256) void cast_w1_kernel(
    const float* __restrict__ w1, __hip_bfloat16* __restrict__ o)
{
    int i = blockIdx.x * 256 + threadIdx.x;
    if (i < HIDN * FAN1) o[i] = __float2bfloat16(w1[i]);
}

// ------- prop hop: wave/node; two 32-lane halves, one edge each, 8B/lane ---
__global__ __launch_bounds__(256) void prop_kernel(
    const __hip_bfloat16* __restrict__ x, int xstride,
    __hip_bfloat16* __restrict__ y, int ystride,
    const int* __restrict__ row_ptr, const int* __restrict__ cols,
    const float* __restrict__ nrm)
{
    int gw = (blockIdx.x * 256 + threadIdx.x) >> 6;
    if (gw >= NNODES) return;
    int lane = threadIdx.x & 63;
    int half = lane >> 5, sl = lane & 31;
    int beg = row_ptr[gw], end = row_ptr[gw + 1];
    float a0 = 0.f, a1 = 0.f, a2 = 0.f, a3 = 0.f;
    int e = beg + half;
    for (; e + 6 < end; e += 8) {   // this lane: e, e+2, e+4, e+6
        int s0 = cols[e], s1 = cols[e + 2], s2 = cols[e + 4], s3 = cols[e + 6];
        float w0 = nrm[e], w1 = nrm[e + 2], w2 = nrm[e + 4], w3 = nrm[e + 6];
        uint2 u0 = *(const uint2*)(x + (size_t)s0 * xstride + sl * 4);
        uint2 u1 = *(const uint2*)(x + (size_t)s1 * xstride + sl * 4);
        uint2 u2 = *(const uint2*)(x + (size_t)s2 * xstride + sl * 4);
        uint2 u3 = *(const uint2*)(x + (size_t)s3 * xstride + sl * 4);
        a0 += w0 * bf16lo(u0.x); a1 += w0 * bf16hi(u0.x);
        a2 += w0 * bf16lo(u0.y); a3 += w0 * bf16hi(u0.y);
        a0 += w1 * bf16lo(u1.x); a1 += w1 * bf16hi(u1.x);
        a2 += w1 * bf16lo(u1.y); a3 += w1 * bf16hi(u1.y);
        a0 += w2 * bf16lo(u2.x); a1 += w2 * bf16hi(u2.x);
        a2 += w2 * bf16lo(u2.y); a3 += w2 * bf16hi(u2.y);
        a0 += w3 * bf16lo(u3.x); a1 += w3 * bf16hi(u3.x);
        a2 += w3 * bf16lo(u3.y); a3 += w3 * bf16hi(u3.y);
    }
    for (; e < end; e += 2) {
        int s0 = cols[e];
        float w0 = nrm[e];
        uint2 u0 = *(const uint2*)(x + (size_t)s0 * xstride + sl * 4);
        a0 += w0 * bf16lo(u0.x); a1 += w0 * bf16hi(u0.x);
        a2 += w0 * bf16lo(u0.y); a3 += w0 * bf16hi(u0.y);
    }
    a0 += __shfl_xor(a0, 32, 64);
    a1 += __shfl_xor(a1, 32, 64);
    a2 += __shfl_xor(a2, 32, 64);
    a3 += __shfl_xor(a3, 32, 64);
    if (half == 0) {
        uint2 o;
        o.x = packbf(a0, a1);
        o.y = packbf(a2, a3);
        *(uint2*)(y + (size_t)gw * ystride + sl * 4) = o;
    }
}

// ---------------- fc1 BIG: one launch, K=1152, 128x128 tile, BK=32 --------
// grid (4, 782): n-tile fast for A-tile L2 reuse
__global__ __launch_bounds__(256) void fc1_big_kernel(
    const __hip_bfloat16* __restrict__ h0, const __hip_bfloat16* __restrict__ w1,
    const float* __restrict__ b1, __hip_bfloat16* __restrict__ h1,
    float* __restrict__ gsum, float* __restrict__ gsq)
{
    __shared__ char smem[33792];   // As 8K | Bs 8K ; epilogue: tile 32K + stats 1K
    char* As = smem;
    char* Bs = smem + 8192;

    int n0 = blockIdx.x * 128;
    int m0 = blockIdx.y * 128;
    int tid = threadIdx.x, lane = tid & 63, wv = tid >> 6;
    int wr = wv >> 1, wc = wv & 1;

    f32x4 acc[4][4];
    #pragma unroll
    for (int i = 0; i < 4; ++i)
        #pragma unroll
        for (int j = 0; j < 4; ++j)
            acc[i][j] = (f32x4){0.f, 0.f, 0.f, 0.f};

    for (int kt = 0; kt < FAN1 / 32; ++kt) {
        int k0 = kt * 32;
        __syncthreads();
        #pragma unroll
        for (int l = 0; l < 2; ++l) {
            int u = l * 256 + wv * 64 + lane;
            int row = u >> 2, q = u & 3;
            gload16(h0 + (size_t)(m0 + row) * FAN1 + k0 + q * 8,
                    As + (l * 256 + wv * 64) * 16);
            gload16(w1 + (size_t)(n0 + row) * FAN1 + k0 + q * 8,
                    Bs + (l * 256 + wv * 64) * 16);
        }
        __syncthreads();
        short8 af[4], bf[4];
        #pragma unroll
        for (int i = 0; i < 4; ++i)
            af[i] = *(const short8*)(As + (wr * 64 + i * 16 + (lane & 15)) * 64 + (lane >> 4) * 16);
        #pragma unroll
        for (int j = 0; j < 4; ++j)
            bf[j] = *(const short8*)(Bs + (wc * 64 + j * 16 + (lane & 15)) * 64 + (lane >> 4) * 16);
        #pragma unroll
        for (int j = 0; j < 4; ++j)
            #pragma unroll
            for (int i = 0; i < 4; ++i)
                acc[i][j] = __builtin_amdgcn_mfma_f32_16x16x32_bf16(af[i], bf[j], acc[i][j], 0, 0, 0);
    }

    // ---- epilogue: bias + lrelu + stats, LDS transpose, coalesced store ----
    __syncthreads();
    __hip_bfloat16* tile = (__hip_bfloat16*)smem;      // [128][128]
    float* lsum = (float*)(smem + 32768);              // [128]
    float* lsq  = lsum + 128;
    if (tid < 128) { lsum[tid] = 0.f; lsq[tid] = 0.f; }
    #pragma unroll
    for (int i = 0; i < 4; ++i) {
        #pragma unroll
        for (int j = 0; j < 4; ++j) {
            int col = wc * 64 + j * 16 + (lane & 15);
            #pragma unroll
            for (int r = 0; r < 4; ++r) {
                int row = wr * 64 + i * 16 + (lane >> 4) * 4 + r;
                tile[row * 128 + col] = __float2bfloat16(acc[i][j][r]);
            }
        }
    }
    __syncthreads();

    int cu = tid & 15, tr = tid >> 4;
    float bias[8];
    float s[8], q[8];
    #pragma unroll
    for (int e = 0; e < 8; ++e) { s[e] = 0.f; q[e] = 0.f; }
    #pragma unroll
    for (int e = 0; e < 8; ++e) bias[e] = b1[n0 + cu * 8 + e];
    for (int p = 0; p < 8; ++p) {
        int row = p * 16 + tr;
        int gm = m0 + row;
        if (gm >= NNODES) continue;
        short8 fresh = *(const short8*)(tile + row * 128 + cu * 8);
        size_t gidx = (size_t)gm * HIDN + n0 + cu * 8;
        float v[8];
        #pragma unroll
        for (int e = 0; e < 8; ++e) {
            float t = bf16s(fresh[e]) + bias[e];
            t = (t > 0.f) ? t : 0.2f * t;
            v[e] = t;
            s[e] += t;
            q[e] += t * t;
        }
        short8 outv;
        #pragma unroll
        for (int e = 0; e < 8; ++e) outv[e] = (short)__bfloat16_as_ushort(__float2bfloat16(v[e]));
        *(short8*)(h1 + gidx) = outv;
    }
    #pragma unroll
    for (int e = 0; e < 8; ++e) {
        atomicAdd(&lsum[cu * 8 + e], s[e]);
        atomicAdd(&lsq[cu * 8 + e], q[e]);
    }
    __syncthreads();
    if (tid < 128) {
        atomicAdd(&gsum[n0 + tid], lsum[tid]);
        atomicAdd(&gsq[n0 + tid], lsq[tid]);
    }
}

// ---------------- fc1 SMALL (fallback): K=384 slices, RMW ----------------
__global__ __launch_bounds__(256) void fc1_small_kernel(
    const __hip_bfloat16* __restrict__ xb0, const __hip_bfloat16* __restrict__ xb1,
    const __hip_bfloat16* __restrict__ xb2, const __hip_bfloat16* __restrict__ w1,
    const float* __restrict__ b1, __hip_bfloat16* __restrict__ h1acc,
    float* __restrict__ gsum, float* __restrict__ gsq, int gsel, int mode)
{
    __shared__ char smem[33792];
    char* As = smem;
    char* Bs = smem + 8192;

    int m0 = blockIdx.y * 128;
    int n0 = blockIdx.x * 128;
    int tid = threadIdx.x, lane = tid & 63, wv = tid >> 6;
    int wr = wv >> 1, wc = wv & 1;
    int kbase = gsel * 384;

    f32x4 acc[4][4];
    #pragma unroll
    for (int i = 0; i < 4; ++i)
        #pragma unroll
        for (int j = 0; j < 4; ++j)
            acc[i][j] = (f32x4){0.f, 0.f, 0.f, 0.f};

    const __hip_bfloat16* xs[3] = {xb0, xb1, xb2};

    for (int kt = 0; kt < 12; ++kt) {
        const __hip_bfloat16* xp = xs[kt >> 2];
        int koff = (kt & 3) * 32;
        int kglob = kbase + kt * 32;
        __syncthreads();
        #pragma unroll
        for (int l = 0; l < 2; ++l) {
            int u = l * 256 + wv * 64 + lane;
            int row = u >> 2, q = u & 3;
            gload16(xp + (size_t)(m0 + row) * DFEAT + koff + q * 8,
                    As + (l * 256 + wv * 64) * 16);
            gload16(w1 + (size_t)(n0 + row) * FAN1 + kglob + q * 8,
                    Bs + (l * 256 + wv * 64) * 16);
        }
        __syncthreads();
        short8 af[4], bf[4];
        #pragma unroll
        for (int i = 0; i < 4; ++i)
            af[i] = *(const short8*)(As + (wr * 64 + i * 16 + (lane & 15)) * 64 + (lane >> 4) * 16);
        #pragma unroll
        for (int j = 0; j < 4; ++j)
            bf[j] = *(const short8*)(Bs + (wc * 64 + j * 16 + (lane & 15)) * 64 + (lane >> 4) * 16);
        #pragma unroll
        for (int j = 0; j < 4; ++j)
            #pragma unroll
            for (int i = 0; i < 4; ++i)
                acc[i][j] = __builtin_amdgcn_mfma_f32_16x16x32_bf16(af[i], bf[j], acc[i][j], 0, 0, 0);
    }

    __syncthreads();
    __hip_bfloat16* tile = (__hip_bfloat16*)smem;
    float* lsum = (float*)(smem + 32768);
    float* lsq  = lsum + 128;
    if (mode == 2 && tid < 128) { lsum[tid] = 0.f; lsq[tid] = 0.f; }
    #pragma unroll
    for (int i = 0; i < 4; ++i) {
        #pragma unroll
        for (int j = 0; j < 4; ++j) {
            int col = wc * 64 + j * 16 + (lane & 15);
            #pragma unroll
            for (int r = 0; r < 4; ++r) {
                int row = wr * 64 + i * 16 + (lane >> 4) * 4 + r;
                tile[row * 128 + col] = __float2bfloat16(acc[i][j][r]);
            }
        }
    }
    __syncthreads();

    int cu = tid & 15, tr = tid >> 4;
    float bias[8];
    float s[8], q[8];
    #pragma unroll
    for (int e = 0; e < 8; ++e) { s[e] = 0.f; q[e] = 0.f; }
    if (mode == 2) {
        #pragma unroll
        for (int e = 0; e < 8; ++e) bias[e] = b1[n0 + cu * 8 + e];
    }
    for (int p = 0; p < 8; ++p) {
        int row = p * 16 + tr;
        int gm = m0 + row;
        if (gm >= NNODES) continue;
        short8 fresh = *(const short8*)(tile + row * 128 + cu * 8);
        size_t gidx = (size_t)gm * HIDN + n0 + cu * 8;
        float v[8];
        #pragma unroll
        for (int e = 0; e < 8; ++e) v[e] = bf16s(fresh[e]);
        if (mode != 0) {
            short8 prev = *(const short8*)(h1acc + gidx);
            #pragma unroll
            for (int e = 0; e < 8; ++e) v[e] += bf16s(prev[e]);
        }
        if (mode == 2) {
            #pragma unroll
            for (int e = 0; e < 8; ++e) {
                float t = v[e] + bias[e];
                t = (t > 0.f) ? t : 0.2f * t;
                v[e] = t;
                s[e] += t;
                q[e] += t * t;
            }
        }
        short8 outv;
        #pragma unroll
        for (int e = 0; e < 8; ++e) outv[e] = (short)__bfloat16_as_ushort(__float2bfloat16(v[e]));
        *(short8*)(h1acc + gidx) = outv;
    }
    if (mode == 2) {
        #pragma unroll
        for (int e = 0; e < 8; ++e) {
            atomicAdd(&lsum[cu * 8 + e], s[e]);
            atomicAdd(&lsq[cu * 8 + e], q[e]);
        }
        __syncthreads();
        if (tid < 128) {
            atomicAdd(&gsum[n0 + tid], lsum[tid]);
            atomicAdd(&gsq[n0 + tid], lsq[tid]);
        }
    }
}

// ---------------- BN finalize: fold into W2 + const vector ----------------
__global__ __launch_bounds__(512) void bn_finalize(
    const float* __restrict__ gsum, const float* __restrict__ gsq,
    const float* __restrict__ gamma, const float* __restrict__ beta,
    const float* __restrict__ w2, const float* __restrict__ b2,
    __hip_bfloat16* __restrict__ w2s, float* __restrict__ cvec)
{
    __shared__ float ts[HIDN];
    int tid = threadIdx.x;              // 512 threads
    float mu = gsum[tid] * (1.0f / NNODES);
    float var = gsq[tid] * (1.0f / NNODES) - mu * mu;
    float s = gamma[tid] * rsqrtf(var + BN_EPS);
    float t = beta[tid] - mu * s;
    ts[tid] = t;
    for (int o = 0; o < OUTD; ++o)
        w2s[o * HIDN + tid] = __float2bfloat16(w2[o * HIDN + tid] * s);
    __syncthreads();
    int lane = tid & 63, wv = tid >> 6; // 8 waves
    for (int o = wv; o < OUTD; o += 8) {
        float p = 0.f;
        for (int j = lane; j < HIDN; j += 64) p += ts[j] * w2[o * HIDN + j];
        #pragma unroll
        for (int off = 32; off; off >>= 1) p += __shfl_xor(p, off, 64);
        if (lane == 0) cvec[o] = p + b2[o];
    }
}

// ---------------- fc2: [N,512]x[512,32] bf16 MFMA ----------------
__global__ __launch_bounds__(256) void fc2_kernel(
    const __hip_bfloat16* __restrict__ h1, const __hip_bfloat16* __restrict__ w2s,
    const float* __restrict__ cvec, float* __restrict__ out)
{
    int gw = (blockIdx.x * 256 + threadIdx.x) >> 6;
    if (gw >= NNODES / 16) return;
    int lane = threadIdx.x & 63;
    int m0 = gw * 16;
    f32x4 acc[2];
    acc[0] = (f32x4){0.f, 0.f, 0.f, 0.f};
    acc[1] = (f32x4){0.f, 0.f, 0.f, 0.f};
    #pragma unroll
    for (int kt = 0; kt < HIDN / 32; ++kt) {
        int k0 = kt * 32;
        short8 a = *(const short8*)(h1 + (size_t)(m0 + (lane & 15)) * HIDN + k0 + (lane >> 4) * 8);
        #pragma unroll
        for (int j = 0; j < 2; ++j) {
            short8 b = *(const short8*)(w2s + (size_t)(j * 16 + (lane & 15)) * HIDN + k0 + (lane >> 4) * 8);
            acc[j] = __builtin_amdgcn_mfma_f32_16x16x32_bf16(a, b, acc[j], 0, 0, 0);
        }
    }
    #pragma unroll
    for (int j = 0; j < 2; ++j) {
        int col = j * 16 + (lane & 15);
        float cadd = cvec[col];
        #pragma unroll
        for (int r = 0; r < 4; ++r) {
            int row = m0 + (lane >> 4) * 4 + r;
            out[(size_t)row * OUTD + col] = acc[j][r] + cadd;
        }
    }
}

// ---------------- host ----------------
struct Ptrs {
    float *deg, *nrm, *gsum, *gsq, *cvec;
    int *cnt, *fillc, *row_ptr, *colsb;
    __hip_bfloat16 *h0, *xs0, *xs1, *xs2, *h1acc, *w1b, *w2s;
};

static size_t layout(char* base, bool big, Ptrs& P) {
    char* p = base;
    auto take = [&](size_t b) {
        char* q = (char*)(((uintptr_t)p + 255) & ~(uintptr_t)255);
        p = q + b;
        return q;
    };
    P.deg     = (float*)take((size_t)NNODES * 4);
    P.cnt     = (int*)  take((size_t)NNODES * 4);
    P.fillc   = (int*)  take((size_t)NNODES * 4);
    P.row_ptr = (int*)  take((size_t)(NNODES + 1) * 4);
    P.colsb   = (int*)  take((size_t)NEDGE * 4);
    P.nrm     = (float*)take((size_t)NEDGE * 4);
    P.h1acc   = (__hip_bfloat16*)take((size_t)NNODES * HIDN * 2);
    P.w1b     = (__hip_bfloat16*)take((size_t)HIDN * FAN1 * 2);
    P.w2s     = (__hip_bfloat16*)take((size_t)OUTD * HIDN * 2);
    P.gsum    = (float*)take(HIDN * 4);
    P.gsq     = (float*)take(HIDN * 4);
    P.cvec    = (float*)take(OUTD * 4);
    if (big) {
        // +512KB slack: fc1 A-staging reads up to 96 rows past N on last m-tile
        P.h0 = (__hip_bfloat16*)take((size_t)NNODES * FAN1 * 2 + 512 * 1024);
        P.xs0 = P.xs1 = P.xs2 = nullptr;
    } else {
        P.xs0 = (__hip_bfloat16*)take((size_t)NNODES * DFEAT * 2);
        P.xs1 = (__hip_bfloat16*)take((size_t)NNODES * DFEAT * 2);
        P.xs2 = (__hip_bfloat16*)take((size_t)NNODES * DFEAT * 2 + 64 * 1024);
        P.h0 = nullptr;
    }
    return (size_t)(p - base);
}

extern "C" void kernel_launch(void* const* d_in, const int* in_sizes, int n_in,
                              void* d_out, int out_size, void* d_ws, size_t ws_size,
                              hipStream_t stream)
{
    const float* feature = (const float*)d_in[0];
    const float* coor    = (const float*)d_in[1];
    const float* theta   = (const float*)d_in[2];
    const float* W1      = (const float*)d_in[3];
    const float* b1      = (const float*)d_in[4];
    const float* gamma   = (const float*)d_in[5];
    const float* beta    = (const float*)d_in[6];
    const float* W2      = (const float*)d_in[7];
    const float* b2      = (const float*)d_in[8];
    const int*   ei      = (const int*)d_in[9];
    const int*   mm      = (const int*)d_in[10];
    float* out = (float*)d_out;
    (void)in_sizes; (void)n_in; (void)out_size;

    Ptrs P;
    size_t need_big = layout((char*)0, true, P);
    bool big = (ws_size >= need_big);
    layout((char*)d_ws, big, P);

    hipMemsetAsync(P.deg,   0, (size_t)NNODES * 4, stream);
    hipMemsetAsync(P.cnt,   0, (size_t)NNODES * 4, stream);
    hipMemsetAsync(P.fillc, 0, (size_t)NNODES * 4, stream);
    hipMemsetAsync(P.gsum,  0, HIDN * 4, stream);
    hipMemsetAsync(P.gsq,   0, HIDN * 4, stream);

    int eb = (NEDGE + 255) / 256;
    edge_kernel<<<eb, 256, 0, stream>>>(ei, coor, theta, mm, P.deg, P.cnt);
    scan_kernel<<<1, 1024, 0, stream>>>(P.cnt, P.row_ptr, NNODES);
    fill_kernel<<<eb, 256, 0, stream>>>(ei, coor, theta, mm, P.deg, P.row_ptr,
                                        P.fillc, P.colsb, P.nrm);

    cast_w1_kernel<<<(HIDN * FAN1 + 255) / 256, 256, 0, stream>>>(W1, P.w1b);

    int pb = (NNODES * 64) / 256;
    int cb = (NNODES * 64) / 256;

    if (big) {
        cast_feat_kernel<<<cb, 256, 0, stream>>>(feature, P.h0, FAN1);
        for (int k = 1; k <= KHOP; ++k) {
            prop_kernel<<<pb, 256, 0, stream>>>(P.h0 + (size_t)(k - 1) * DFEAT, FAN1,
                                                P.h0 + (size_t)k * DFEAT, FAN1,
                                                P.row_ptr, P.colsb, P.nrm);
        }
        dim3 fgrid(4, (NNODES + 127) / 128);
        fc1_big_kernel<<<fgrid, 256, 0, stream>>>(P.h0, P.w1b, b1, P.h1acc,
                                                  P.gsum, P.gsq);
    } else {
        cast_feat_kernel<<<cb, 256, 0, stream>>>(feature, P.xs0, DFEAT);
        dim3 fgrid(4, (NNODES + 127) / 128);
        __hip_bfloat16* slot[3] = {P.xs0, P.xs1, P.xs2};
        int cur = 0, gcount = 0;
        for (int k = 1; k <= KHOP; ++k) {
            int nxt = k % 3;
            prop_kernel<<<pb, 256, 0, stream>>>(slot[cur], DFEAT, slot[nxt], DFEAT,
                                                P.row_ptr, P.colsb, P.nrm);
            cur = nxt;
            if (k % 3 == 2) {
                int mode = (gcount == 0) ? 0 : 1;
                fc1_small_kernel<<<fgrid, 256, 0, stream>>>(P.xs0, P.xs1, P.xs2,
                    P.w1b, b1, P.h1acc, P.gsum, P.gsq, gcount, mode);
                ++gcount;
            }
        }
        fc1_small_kernel<<<fgrid, 256, 0, stream>>>(P.xs0, P.xs1, P.xs2,
            P.w1b, b1, P.h1acc, P.gsum, P.gsq, gcount, 2);
    }

    bn_finalize<<<1, 512, 0, stream>>>(P.gsum, P.gsq, gamma, beta, W2, b2,
                                       P.w2s, P.cvec);
    fc2_kernel<<<(NNODES / 16 * 64 + 255) / 256, 256, 0, stream>>>(P.h1acc, P.w2s,
                                                                   P.cvec, out);
}

// Round 5
// 1058.610 us; speedup vs baseline: 1.9246x; 1.2055x over previous
//
#include <hip/hip_runtime.h>
#include <hip/hip_bf16.h>
#include <cstdint>
#include <cstddef>

#define NNODES 100000
#define DFEAT 128
#define KHOP 8
#define FAN1 1152        // D*(K+1)
#define HIDN 512
#define OUTD 32
#define NEDGE 1600000
#define BN_EPS 1e-5f
#define DEG_EPS 1e-8f

using short8 = __attribute__((ext_vector_type(8))) short;
using f32x4  = __attribute__((ext_vector_type(4))) float;

__device__ __forceinline__ float bf16lo(uint32_t u) { return __uint_as_float(u << 16); }
__device__ __forceinline__ float bf16hi(uint32_t u) { return __uint_as_float(u & 0xffff0000u); }
__device__ __forceinline__ float bf16s(short x) {
    return __uint_as_float(((uint32_t)(uint16_t)x) << 16);
}
__device__ __forceinline__ uint32_t packbf(float a, float b) {
    uint32_t lo = __bfloat16_as_ushort(__float2bfloat16(a));
    uint32_t hi = __bfloat16_as_ushort(__float2bfloat16(b));
    return lo | (hi << 16);
}

__device__ __forceinline__ void gload16(const void* g, void* l) {
    __builtin_amdgcn_global_load_lds(
        (const __attribute__((address_space(1))) uint32_t*)g,
        (__attribute__((address_space(3))) uint32_t*)l, 16, 0, 0);
}

struct Blk9 { const __hip_bfloat16* p[9]; };

// ---------------- edge weights + degree + histogram ----------------
__global__ __launch_bounds__(256) void edge_kernel(
    const int* __restrict__ ei, const float* __restrict__ coor,
    const float* __restrict__ theta, const int* __restrict__ mm,
    float* __restrict__ deg, int* __restrict__ cnt)
{
    int e = blockIdx.x * 256 + threadIdx.x;
    if (e >= NEDGE) return;
    float tom = theta[0] / (float)mm[0];
    int r = ei[e], c = ei[NEDGE + e];
    float2 pr = *(const float2*)(coor + 2*(size_t)r);
    float2 pc = *(const float2*)(coor + 2*(size_t)c);
    float dx = pr.x - pc.x, dy = pr.y - pc.y;
    float w = expf(-(dx*dx + dy*dy) * tom);
    atomicAdd(&deg[r], w);
    atomicAdd(&cnt[r], 1);
}

// ---------------- 3-phase parallel scan ----------------
__global__ __launch_bounds__(1024) void scan_local(
    const int* __restrict__ cnt, int* __restrict__ row_ptr,
    int* __restrict__ bsum, int n)
{
    __shared__ int wsum[16];
    int b = blockIdx.x, tid = threadIdx.x;
    int i = b * 1024 + tid;
    int lane = tid & 63, wv = tid >> 6;
    int v = (i < n) ? cnt[i] : 0;
    #pragma unroll
    for (int off = 1; off < 64; off <<= 1) {
        int t = __shfl_up(v, off, 64);
        if (lane >= off) v += t;
    }
    if (lane == 63) wsum[wv] = v;
    __syncthreads();
    if (tid < 16) {
        int t = wsum[tid];
        #pragma unroll
        for (int off = 1; off < 16; off <<= 1) {
            int u = __shfl_up(t, off, 64);
            if (tid >= off) t += u;
        }
        wsum[tid] = t;
    }
    __syncthreads();
    int incl = v + ((wv == 0) ? 0 : wsum[wv - 1]);
    if (i < n) row_ptr[i + 1] = incl;
    if (tid == 0) bsum[b] = wsum[15];
}

__global__ __launch_bounds__(128) void scan_carry(int* __restrict__ bsum, int n)
{
    __shared__ int ws[2];
    int tid = threadIdx.x, lane = tid & 63, wv = tid >> 6;
    int v = (tid < n) ? bsum[tid] : 0;
    int incl = v;
    #pragma unroll
    for (int off = 1; off < 64; off <<= 1) {
        int t = __shfl_up(incl, off, 64);
        if (lane >= off) incl += t;
    }
    if (lane == 63) ws[wv] = incl;
    __syncthreads();
    int excl = incl - v + ((wv == 0) ? 0 : ws[0]);
    if (tid < n) bsum[tid] = excl;
}

__global__ __launch_bounds__(256) void scan_add(
    const int* __restrict__ bsum, int* __restrict__ row_ptr, int n)
{
    int i = blockIdx.x * 256 + threadIdx.x;
    if (i == 0) row_ptr[0] = 0;
    if (i < n) row_ptr[i + 1] += bsum[i >> 10];
}

// ---------------- CSR fill + norm (recompute w) ----------------
__global__ __launch_bounds__(256) void fill_kernel(
    const int* __restrict__ ei, const float* __restrict__ coor,
    const float* __restrict__ theta, const int* __restrict__ mm,
    const float* __restrict__ deg, const int* __restrict__ row_ptr,
    int* __restrict__ fill, int* __restrict__ cols, float* __restrict__ nrm)
{
    int e = blockIdx.x * 256 + threadIdx.x;
    if (e >= NEDGE) return;
    float tom = theta[0] / (float)mm[0];
    int r = ei[e], c = ei[NEDGE + e];
    float2 pr = *(const float2*)(coor + 2*(size_t)r);
    float2 pc = *(const float2*)(coor + 2*(size_t)c);
    float dx = pr.x - pc.x, dy = pr.y - pc.y;
    float w = expf(-(dx*dx + dy*dy) * tom);
    int pos = row_ptr[r] + atomicAdd(&fill[r], 1);
    cols[pos] = c;
    nrm[pos] = w / (deg[r] + DEG_EPS);
}

// ---------------- cast feature -> bf16 slot ([N,128]) ----------------
__global__ __launch_bounds__(256) void cast_feat_kernel(
    const float* __restrict__ f, __hip_bfloat16* __restrict__ x0)
{
    int i = blockIdx.x * 256 + threadIdx.x;      // over N*64 float2 units
    int node = i >> 6, l2 = i & 63;
    if (node >= NNODES) return;
    float2 v = *(const float2*)(f + (size_t)node * DFEAT + l2 * 2);
    __hip_bfloat162 hb;
    hb.x = __float2bfloat16(v.x);
    hb.y = __float2bfloat16(v.y);
    *(__hip_bfloat162*)(x0 + (size_t)node * DFEAT + l2 * 2) = hb;
}

// ---------------- cast W1 -> bf16 ----------------
__global__ __launch_bounds__(256) void cast_w1_kernel(
    const float* __restrict__ w1, __hip_bfloat16* __restrict__ o)
{
    int i = blockIdx.x * 256 + threadIdx.x;
    if (i < HIDN * FAN1) o[i] = __float2bfloat16(w1[i]);
}

// ------- prop hop: wave/node; 4 quarter-lanes own edge streams, 16B/lane ---
__global__ __launch_bounds__(256) void prop_kernel(
    const __hip_bfloat16* __restrict__ x, __hip_bfloat16* __restrict__ y,
    const int* __restrict__ row_ptr, const int* __restrict__ cols,
    const float* __restrict__ nrm)
{
    int gw = (blockIdx.x * 256 + threadIdx.x) >> 6;
    if (gw >= NNODES) return;
    int lane = threadIdx.x & 63;
    int q = lane >> 4, sl = lane & 15;
    int beg = row_ptr[gw], end = row_ptr[gw + 1];
    float a0 = 0.f, a1 = 0.f, a2 = 0.f, a3 = 0.f;
    float a4 = 0.f, a5 = 0.f, a6 = 0.f, a7 = 0.f;
    int e = beg + q;
    for (; e + 12 < end; e += 16) {   // this lane: e, e+4, e+8, e+12
        int s0 = cols[e], s1 = cols[e + 4], s2 = cols[e + 8], s3 = cols[e + 12];
        float w0 = nrm[e], w1 = nrm[e + 4], w2 = nrm[e + 8], w3 = nrm[e + 12];
        uint4 u0 = *(const uint4*)(x + (size_t)s0 * DFEAT + sl * 8);
        uint4 u1 = *(const uint4*)(x + (size_t)s1 * DFEAT + sl * 8);
        uint4 u2 = *(const uint4*)(x + (size_t)s2 * DFEAT + sl * 8);
        uint4 u3 = *(const uint4*)(x + (size_t)s3 * DFEAT + sl * 8);
        a0 += w0 * bf16lo(u0.x); a1 += w0 * bf16hi(u0.x);
        a2 += w0 * bf16lo(u0.y); a3 += w0 * bf16hi(u0.y);
        a4 += w0 * bf16lo(u0.z); a5 += w0 * bf16hi(u0.z);
        a6 += w0 * bf16lo(u0.w); a7 += w0 * bf16hi(u0.w);
        a0 += w1 * bf16lo(u1.x); a1 += w1 * bf16hi(u1.x);
        a2 += w1 * bf16lo(u1.y); a3 += w1 * bf16hi(u1.y);
        a4 += w1 * bf16lo(u1.z); a5 += w1 * bf16hi(u1.z);
        a6 += w1 * bf16lo(u1.w); a7 += w1 * bf16hi(u1.w);
        a0 += w2 * bf16lo(u2.x); a1 += w2 * bf16hi(u2.x);
        a2 += w2 * bf16lo(u2.y); a3 += w2 * bf16hi(u2.y);
        a4 += w2 * bf16lo(u2.z); a5 += w2 * bf16hi(u2.z);
        a6 += w2 * bf16lo(u2.w); a7 += w2 * bf16hi(u2.w);
        a0 += w3 * bf16lo(u3.x); a1 += w3 * bf16hi(u3.x);
        a2 += w3 * bf16lo(u3.y); a3 += w3 * bf16hi(u3.y);
        a4 += w3 * bf16lo(u3.z); a5 += w3 * bf16hi(u3.z);
        a6 += w3 * bf16lo(u3.w); a7 += w3 * bf16hi(u3.w);
    }
    for (; e < end; e += 4) {
        int s0 = cols[e];
        float w0 = nrm[e];
        uint4 u0 = *(const uint4*)(x + (size_t)s0 * DFEAT + sl * 8);
        a0 += w0 * bf16lo(u0.x); a1 += w0 * bf16hi(u0.x);
        a2 += w0 * bf16lo(u0.y); a3 += w0 * bf16hi(u0.y);
        a4 += w0 * bf16lo(u0.z); a5 += w0 * bf16hi(u0.z);
        a6 += w0 * bf16lo(u0.w); a7 += w0 * bf16hi(u0.w);
    }
    a0 += __shfl_xor(a0, 16, 64); a0 += __shfl_xor(a0, 32, 64);
    a1 += __shfl_xor(a1, 16, 64); a1 += __shfl_xor(a1, 32, 64);
    a2 += __shfl_xor(a2, 16, 64); a2 += __shfl_xor(a2, 32, 64);
    a3 += __shfl_xor(a3, 16, 64); a3 += __shfl_xor(a3, 32, 64);
    a4 += __shfl_xor(a4, 16, 64); a4 += __shfl_xor(a4, 32, 64);
    a5 += __shfl_xor(a5, 16, 64); a5 += __shfl_xor(a5, 32, 64);
    a6 += __shfl_xor(a6, 16, 64); a6 += __shfl_xor(a6, 32, 64);
    a7 += __shfl_xor(a7, 16, 64); a7 += __shfl_xor(a7, 32, 64);
    if (q == 0) {
        uint4 o;
        o.x = packbf(a0, a1);
        o.y = packbf(a2, a3);
        o.z = packbf(a4, a5);
        o.w = packbf(a6, a7);
        *(uint4*)(y + (size_t)gw * DFEAT + sl * 8) = o;
    }
}

// ---------------- unified fc1 GEMM: 128x128 tile, BK=64, XOR-swizzled LDS --
// grid (4, 782); mode bit0 = RMW accumulate, bit1 = finalize (bias+lrelu+stats)
__global__ __launch_bounds__(256) void fc1_kernel(
    Blk9 blks, const __hip_bfloat16* __restrict__ w1,
    const float* __restrict__ b1, __hip_bfloat16* __restrict__ h1,
    float* __restrict__ gsum, float* __restrict__ gsq,
    int nblk, int kb0, int mode)
{
    __shared__ char smem[33792];   // As 16K | Bs 16K ; epilogue: tile 32K + stats 1K
    char* As = smem;
    char* Bs = smem + 16384;

    int n0 = blockIdx.x * 128;
    int m0 = blockIdx.y * 128;
    int tid = threadIdx.x, lane = tid & 63, wv = tid >> 6;
    int wr = wv >> 1, wc = wv & 1;

    f32x4 acc[4][4];
    #pragma unroll
    for (int i = 0; i < 4; ++i)
        #pragma unroll
        for (int j = 0; j < 4; ++j)
            acc[i][j] = (f32x4){0.f, 0.f, 0.f, 0.f};

    for (int kb = 0; kb < nblk; ++kb) {
        const __hip_bfloat16* xp = blks.p[kb];
        int kglob = (kb0 + kb) * 128;
        #pragma unroll
        for (int half = 0; half < 2; ++half) {
            int koff = half * 64;
            __syncthreads();
            // stage A(128x64) + B(128x64): linear LDS dest, inverse-swizzled src
            #pragma unroll
            for (int l = 0; l < 4; ++l) {
                int u = l * 256 + wv * 64 + lane;
                int row = u >> 3;
                int ch = (u & 7) ^ (row & 7);
                gload16(xp + (size_t)(m0 + row) * DFEAT + koff + ch * 8,
                        As + (l * 256 + wv * 64) * 16);
                gload16(w1 + (size_t)(n0 + row) * FAN1 + kglob + koff + ch * 8,
                        Bs + (l * 256 + wv * 64) * 16);
            }
            __syncthreads();
            #pragma unroll
            for (int ks = 0; ks < 2; ++ks) {
                short8 af[4], bfr[4];
                #pragma unroll
                for (int i = 0; i < 4; ++i) {
                    int row = wr * 64 + i * 16 + (lane & 15);
                    int ch = (ks * 4 + (lane >> 4)) ^ (row & 7);
                    af[i] = *(const short8*)(As + row * 128 + ch * 16);
                }
                #pragma unroll
                for (int j = 0; j < 4; ++j) {
                    int row = wc * 64 + j * 16 + (lane & 15);
                    int ch = (ks * 4 + (lane >> 4)) ^ (row & 7);
                    bfr[j] = *(const short8*)(Bs + row * 128 + ch * 16);
                }
                #pragma unroll
                for (int j = 0; j < 4; ++j)
                    #pragma unroll
                    for (int i = 0; i < 4; ++i)
                        acc[i][j] = __builtin_amdgcn_mfma_f32_16x16x32_bf16(af[i], bfr[j], acc[i][j], 0, 0, 0);
            }
        }
    }

    // ---- epilogue: LDS transpose, coalesced (RMW) store, optional stats ----
    __syncthreads();
    __hip_bfloat16* tile = (__hip_bfloat16*)smem;      // [128][128]
    float* lsum = (float*)(smem + 32768);              // [128]
    float* lsq  = lsum + 128;
    bool fin = (mode & 2) != 0;
    if (fin && tid < 128) { lsum[tid] = 0.f; lsq[tid] = 0.f; }
    #pragma unroll
    for (int i = 0; i < 4; ++i) {
        #pragma unroll
        for (int j = 0; j < 4; ++j) {
            int col = wc * 64 + j * 16 + (lane & 15);
            #pragma unroll
            for (int r = 0; r < 4; ++r) {
                int row = wr * 64 + i * 16 + (lane >> 4) * 4 + r;
                tile[row * 128 + col] = __float2bfloat16(acc[i][j][r]);
            }
        }
    }
    __syncthreads();

    int cu = tid & 15, tr = tid >> 4;
    float bias[8];
    float s[8], q[8];
    #pragma unroll
    for (int e = 0; e < 8; ++e) { s[e] = 0.f; q[e] = 0.f; }
    if (fin) {
        #pragma unroll
        for (int e = 0; e < 8; ++e) bias[e] = b1[n0 + cu * 8 + e];
    }
    for (int p = 0; p < 8; ++p) {
        int row = p * 16 + tr;
        int gm = m0 + row;
        if (gm >= NNODES) continue;
        short8 fresh = *(const short8*)(tile + row * 128 + cu * 8);
        size_t gidx = (size_t)gm * HIDN + n0 + cu * 8;
        float v[8];
        #pragma unroll
        for (int e = 0; e < 8; ++e) v[e] = bf16s(fresh[e]);
        if (mode & 1) {
            short8 prev = *(const short8*)(h1 + gidx);
            #pragma unroll
            for (int e = 0; e < 8; ++e) v[e] += bf16s(prev[e]);
        }
        if (fin) {
            #pragma unroll
            for (int e = 0; e < 8; ++e) {
                float t = v[e] + bias[e];
                t = (t > 0.f) ? t : 0.2f * t;
                v[e] = t;
                s[e] += t;
                q[e] += t * t;
            }
        }
        short8 outv;
        #pragma unroll
        for (int e = 0; e < 8; ++e) outv[e] = (short)__bfloat16_as_ushort(__float2bfloat16(v[e]));
        *(short8*)(h1 + gidx) = outv;
    }
    if (fin) {
        #pragma unroll
        for (int e = 0; e < 8; ++e) {
            atomicAdd(&lsum[cu * 8 + e], s[e]);
            atomicAdd(&lsq[cu * 8 + e], q[e]);
        }
        __syncthreads();
        if (tid < 128) {
            atomicAdd(&gsum[n0 + tid], lsum[tid]);
            atomicAdd(&gsq[n0 + tid], lsq[tid]);
        }
    }
}

// ---------------- BN finalize: fold into W2 + const vector ----------------
__global__ __launch_bounds__(512) void bn_finalize(
    const float* __restrict__ gsum, const float* __restrict__ gsq,
    const float* __restrict__ gamma, const float* __restrict__ beta,
    const float* __restrict__ w2, const float* __restrict__ b2,
    __hip_bfloat16* __restrict__ w2s, float* __restrict__ cvec)
{
    __shared__ float ts[HIDN];
    int tid = threadIdx.x;              // 512 threads
    float mu = gsum[tid] * (1.0f / NNODES);
    float var = gsq[tid] * (1.0f / NNODES) - mu * mu;
    float s = gamma[tid] * rsqrtf(var + BN_EPS);
    float t = beta[tid] - mu * s;
    ts[tid] = t;
    for (int o = 0; o < OUTD; ++o)
        w2s[o * HIDN + tid] = __float2bfloat16(w2[o * HIDN + tid] * s);
    __syncthreads();
    int lane = tid & 63, wv = tid >> 6; // 8 waves
    for (int o = wv; o < OUTD; o += 8) {
        float p = 0.f;
        for (int j = lane; j < HIDN; j += 64) p += ts[j] * w2[o * HIDN + j];
        #pragma unroll
        for (int off = 32; off; off >>= 1) p += __shfl_xor(p, off, 64);
        if (lane == 0) cvec[o] = p + b2[o];
    }
}

// ---------------- fc2: [N,512]x[512,32] bf16 MFMA ----------------
__global__ __launch_bounds__(256) void fc2_kernel(
    const __hip_bfloat16* __restrict__ h1, const __hip_bfloat16* __restrict__ w2s,
    const float* __restrict__ cvec, float* __restrict__ out)
{
    int gw = (blockIdx.x * 256 + threadIdx.x) >> 6;
    if (gw >= NNODES / 16) return;
    int lane = threadIdx.x & 63;
    int m0 = gw * 16;
    f32x4 acc[2];
    acc[0] = (f32x4){0.f, 0.f, 0.f, 0.f};
    acc[1] = (f32x4){0.f, 0.f, 0.f, 0.f};
    #pragma unroll
    for (int kt = 0; kt < HIDN / 32; ++kt) {
        int k0 = kt * 32;
        short8 a = *(const short8*)(h1 + (size_t)(m0 + (lane & 15)) * HIDN + k0 + (lane >> 4) * 8);
        #pragma unroll
        for (int j = 0; j < 2; ++j) {
            short8 b = *(const short8*)(w2s + (size_t)(j * 16 + (lane & 15)) * HIDN + k0 + (lane >> 4) * 8);
            acc[j] = __builtin_amdgcn_mfma_f32_16x16x32_bf16(a, b, acc[j], 0, 0, 0);
        }
    }
    #pragma unroll
    for (int j = 0; j < 2; ++j) {
        int col = j * 16 + (lane & 15);
        float cadd = cvec[col];
        #pragma unroll
        for (int r = 0; r < 4; ++r) {
            int row = m0 + (lane >> 4) * 4 + r;
            out[(size_t)row * OUTD + col] = acc[j][r] + cadd;
        }
    }
}

// ---------------- host ----------------
struct Ptrs {
    float *deg, *nrm, *gsum, *gsq, *cvec;
    int *cnt, *fillc, *row_ptr, *colsb, *bsum;
    __hip_bfloat16 *slot[9], *h1acc, *w1b, *w2s;
};

static size_t layout(char* base, int nslots, Ptrs& P) {
    char* p = base;
    auto take = [&](size_t b) {
        char* q = (char*)(((uintptr_t)p + 255) & ~(uintptr_t)255);
        p = q + b;
        return q;
    };
    P.deg     = (float*)take((size_t)NNODES * 4);
    P.cnt     = (int*)  take((size_t)NNODES * 4);
    P.fillc   = (int*)  take((size_t)NNODES * 4);
    P.row_ptr = (int*)  take((size_t)(NNODES + 1) * 4);
    P.bsum    = (int*)  take(128 * 4);
    P.colsb   = (int*)  take((size_t)NEDGE * 4);
    P.nrm     = (float*)take((size_t)NEDGE * 4);
    P.h1acc   = (__hip_bfloat16*)take((size_t)NNODES * HIDN * 2);
    P.w1b     = (__hip_bfloat16*)take((size_t)HIDN * FAN1 * 2);
    P.w2s     = (__hip_bfloat16*)take((size_t)OUTD * HIDN * 2);
    P.gsum    = (float*)take(HIDN * 4);
    P.gsq     = (float*)take(HIDN * 4);
    P.cvec    = (float*)take(OUTD * 4);
    for (int i = 0; i < 9; ++i) P.slot[i] = nullptr;
    for (int i = 0; i < nslots; ++i)   // +32KB pad: fc1 A-stage overreads last m-tile
        P.slot[i] = (__hip_bfloat16*)take((size_t)NNODES * DFEAT * 2 + 32768);
    return (size_t)(p - base);
}

extern "C" void kernel_launch(void* const* d_in, const int* in_sizes, int n_in,
                              void* d_out, int out_size, void* d_ws, size_t ws_size,
                              hipStream_t stream)
{
    const float* feature = (const float*)d_in[0];
    const float* coor    = (const float*)d_in[1];
    const float* theta   = (const float*)d_in[2];
    const float* W1      = (const float*)d_in[3];
    const float* b1      = (const float*)d_in[4];
    const float* gamma   = (const float*)d_in[5];
    const float* beta    = (const float*)d_in[6];
    const float* W2      = (const float*)d_in[7];
    const float* b2      = (const float*)d_in[8];
    const int*   ei      = (const int*)d_in[9];
    const int*   mm      = (const int*)d_in[10];
    float* out = (float*)d_out;
    (void)in_sizes; (void)n_in; (void)out_size;

    Ptrs P;
    size_t need9 = layout((char*)0, 9, P);
    size_t need5 = layout((char*)0, 5, P);
    int nslots = (ws_size >= need9) ? 9 : (ws_size >= need5) ? 5 : 3;
    layout((char*)d_ws, nslots, P);

    hipMemsetAsync(P.deg,   0, (size_t)NNODES * 4, stream);
    hipMemsetAsync(P.cnt,   0, (size_t)NNODES * 4, stream);
    hipMemsetAsync(P.fillc, 0, (size_t)NNODES * 4, stream);
    hipMemsetAsync(P.gsum,  0, HIDN * 4, stream);
    hipMemsetAsync(P.gsq,   0, HIDN * 4, stream);

    int eb = (NEDGE + 255) / 256;
    int nchunk = (NNODES + 1023) / 1024;
    edge_kernel<<<eb, 256, 0, stream>>>(ei, coor, theta, mm, P.deg, P.cnt);
    scan_local<<<nchunk, 1024, 0, stream>>>(P.cnt, P.row_ptr, P.bsum, NNODES);
    scan_carry<<<1, 128, 0, stream>>>(P.bsum, nchunk);
    scan_add<<<(NNODES + 255) / 256, 256, 0, stream>>>(P.bsum, P.row_ptr, NNODES);
    fill_kernel<<<eb, 256, 0, stream>>>(ei, coor, theta, mm, P.deg, P.row_ptr,
                                        P.fillc, P.colsb, P.nrm);

    cast_w1_kernel<<<(HIDN * FAN1 + 255) / 256, 256, 0, stream>>>(W1, P.w1b);
    cast_feat_kernel<<<(NNODES * 64) / 256, 256, 0, stream>>>(feature, P.slot[0]);

    int pb = (NNODES * 64) / 256;
    dim3 fgrid(4, (NNODES + 127) / 128);

    auto launch_fc1 = [&](int first_slot, int nblk, int kb0, int mode) {
        Blk9 b;
        for (int i = 0; i < 9; ++i) b.p[i] = P.slot[0];
        for (int i = 0; i < nblk; ++i) b.p[i] = P.slot[(first_slot + i) % nslots];
        fc1_kernel<<<fgrid, 256, 0, stream>>>(b, P.w1b, b1, P.h1acc,
                                              P.gsum, P.gsq, nblk, kb0, mode);
    };

    for (int k = 1; k <= KHOP; ++k) {
        prop_kernel<<<pb, 256, 0, stream>>>(P.slot[(k - 1) % nslots],
                                            P.slot[k % nslots],
                                            P.row_ptr, P.colsb, P.nrm);
        if (nslots == 5 && k == 4) launch_fc1(0, 5, 0, 0);
        if (nslots == 3 && k == 2) launch_fc1(0, 3, 0, 0);
        if (nslots == 3 && k == 5) launch_fc1(0, 3, 3, 1);
    }
    if (nslots == 9) launch_fc1(0, 9, 0, 2);          // single pass, finalize
    if (nslots == 5) launch_fc1(0, 4, 5, 3);          // blocks 5-8 in slots 0-3
    if (nslots == 3) launch_fc1(0, 3, 6, 3);          // blocks 6-8 in slots 0-2

    bn_finalize<<<1, 512, 0, stream>>>(P.gsum, P.gsq, gamma, beta, W2, b2,
                                       P.w2s, P.cvec);
    fc2_kernel<<<(NNODES / 16 * 64 + 255) / 256, 256, 0, stream>>>(P.h1acc, P.w2s,
                                                                   P.cvec, out);
}

// Round 6
// 1012.091 us; speedup vs baseline: 2.0131x; 1.0460x over previous
//
#include <hip/hip_runtime.h>
#include <hip/hip_bf16.h>
#include <cstdint>
#include <cstddef>

#define NNODES 100000
#define DFEAT 128
#define KHOP 8
#define FAN1 1152        // D*(K+1)
#define HIDN 512
#define OUTD 32
#define NEDGE 1600000
#define BN_EPS 1e-5f
#define DEG_EPS 1e-8f

using short8 = __attribute__((ext_vector_type(8))) short;
using f32x4  = __attribute__((ext_vector_type(4))) float;

__device__ __forceinline__ float bf16lo(uint32_t u) { return __uint_as_float(u << 16); }
__device__ __forceinline__ float bf16hi(uint32_t u) { return __uint_as_float(u & 0xffff0000u); }
__device__ __forceinline__ float bf16s(short x) {
    return __uint_as_float(((uint32_t)(uint16_t)x) << 16);
}
__device__ __forceinline__ uint32_t packbf(float a, float b) {
    uint32_t lo = __bfloat16_as_ushort(__float2bfloat16(a));
    uint32_t hi = __bfloat16_as_ushort(__float2bfloat16(b));
    return lo | (hi << 16);
}

__device__ __forceinline__ void gload16(const void* g, void* l) {
    __builtin_amdgcn_global_load_lds(
        (const __attribute__((address_space(1))) uint32_t*)g,
        (__attribute__((address_space(3))) uint32_t*)l, 16, 0, 0);
}

struct Blk9 { const __hip_bfloat16* p[9]; };

// ---------------- edge weights + degree + histogram ----------------
__global__ __launch_bounds__(256) void edge_kernel(
    const int* __restrict__ ei, const float* __restrict__ coor,
    const float* __restrict__ theta, const int* __restrict__ mm,
    float* __restrict__ deg, int* __restrict__ cnt)
{
    int e = blockIdx.x * 256 + threadIdx.x;
    if (e >= NEDGE) return;
    float tom = theta[0] / (float)mm[0];
    int r = ei[e], c = ei[NEDGE + e];
    float2 pr = *(const float2*)(coor + 2*(size_t)r);
    float2 pc = *(const float2*)(coor + 2*(size_t)c);
    float dx = pr.x - pc.x, dy = pr.y - pc.y;
    float w = expf(-(dx*dx + dy*dy) * tom);
    atomicAdd(&deg[r], w);
    atomicAdd(&cnt[r], 1);
}

// ---------------- 3-phase parallel scan ----------------
__global__ __launch_bounds__(1024) void scan_local(
    const int* __restrict__ cnt, int* __restrict__ row_ptr,
    int* __restrict__ bsum, int n)
{
    __shared__ int wsum[16];
    int b = blockIdx.x, tid = threadIdx.x;
    int i = b * 1024 + tid;
    int lane = tid & 63, wv = tid >> 6;
    int v = (i < n) ? cnt[i] : 0;
    #pragma unroll
    for (int off = 1; off < 64; off <<= 1) {
        int t = __shfl_up(v, off, 64);
        if (lane >= off) v += t;
    }
    if (lane == 63) wsum[wv] = v;
    __syncthreads();
    if (tid < 16) {
        int t = wsum[tid];
        #pragma unroll
        for (int off = 1; off < 16; off <<= 1) {
            int u = __shfl_up(t, off, 64);
            if (tid >= off) t += u;
        }
        wsum[tid] = t;
    }
    __syncthreads();
    int incl = v + ((wv == 0) ? 0 : wsum[wv - 1]);
    if (i < n) row_ptr[i + 1] = incl;
    if (tid == 0) bsum[b] = wsum[15];
}

__global__ __launch_bounds__(128) void scan_carry(int* __restrict__ bsum, int n)
{
    __shared__ int ws[2];
    int tid = threadIdx.x, lane = tid & 63, wv = tid >> 6;
    int v = (tid < n) ? bsum[tid] : 0;
    int incl = v;
    #pragma unroll
    for (int off = 1; off < 64; off <<= 1) {
        int t = __shfl_up(incl, off, 64);
        if (lane >= off) incl += t;
    }
    if (lane == 63) ws[wv] = incl;
    __syncthreads();
    int excl = incl - v + ((wv == 0) ? 0 : ws[0]);
    if (tid < n) bsum[tid] = excl;
}

__global__ __launch_bounds__(256) void scan_add(
    const int* __restrict__ bsum, int* __restrict__ row_ptr, int n)
{
    int i = blockIdx.x * 256 + threadIdx.x;
    if (i == 0) row_ptr[0] = 0;
    if (i < n) row_ptr[i + 1] += bsum[i >> 10];
}

// ---------------- CSR fill + norm (recompute w) ----------------
__global__ __launch_bounds__(256) void fill_kernel(
    const int* __restrict__ ei, const float* __restrict__ coor,
    const float* __restrict__ theta, const int* __restrict__ mm,
    const float* __restrict__ deg, const int* __restrict__ row_ptr,
    int* __restrict__ fill, int* __restrict__ cols, float* __restrict__ nrm)
{
    int e = blockIdx.x * 256 + threadIdx.x;
    if (e >= NEDGE) return;
    float tom = theta[0] / (float)mm[0];
    int r = ei[e], c = ei[NEDGE + e];
    float2 pr = *(const float2*)(coor + 2*(size_t)r);
    float2 pc = *(const float2*)(coor + 2*(size_t)c);
    float dx = pr.x - pc.x, dy = pr.y - pc.y;
    float w = expf(-(dx*dx + dy*dy) * tom);
    int pos = row_ptr[r] + atomicAdd(&fill[r], 1);
    cols[pos] = c;
    nrm[pos] = w / (deg[r] + DEG_EPS);
}

// ---------------- cast feature -> bf16 slot ([N,128]) ----------------
__global__ __launch_bounds__(256) void cast_feat_kernel(
    const float* __restrict__ f, __hip_bfloat16* __restrict__ x0)
{
    int i = blockIdx.x * 256 + threadIdx.x;      // over N*64 float2 units
    int node = i >> 6, l2 = i & 63;
    if (node >= NNODES) return;
    float2 v = *(const float2*)(f + (size_t)node * DFEAT + l2 * 2);
    __hip_bfloat162 hb;
    hb.x = __float2bfloat16(v.x);
    hb.y = __float2bfloat16(v.y);
    *(__hip_bfloat162*)(x0 + (size_t)node * DFEAT + l2 * 2) = hb;
}

// ---------------- cast W1 -> bf16 ----------------
__global__ __launch_bounds__(256) void cast_w1_kernel(
    const float* __restrict__ w1, __hip_bfloat16* __restrict__ o)
{
    int i = blockIdx.x * 256 + threadIdx.x;
    if (i < HIDN * FAN1) o[i] = __float2bfloat16(w1[i]);
}

// ------- prop hop: wave/node; 4 quarter-lanes own edge streams, 16B/lane ---
__global__ __launch_bounds__(256) void prop_kernel(
    const __hip_bfloat16* __restrict__ x, __hip_bfloat16* __restrict__ y,
    const int* __restrict__ row_ptr, const int* __restrict__ cols,
    const float* __restrict__ nrm)
{
    int gw = (blockIdx.x * 256 + threadIdx.x) >> 6;
    if (gw >= NNODES) return;
    int lane = threadIdx.x & 63;
    int q = lane >> 4, sl = lane & 15;
    int beg = row_ptr[gw], end = row_ptr[gw + 1];
    float a0 = 0.f, a1 = 0.f, a2 = 0.f, a3 = 0.f;
    float a4 = 0.f, a5 = 0.f, a6 = 0.f, a7 = 0.f;
    int e = beg + q;
    for (; e + 12 < end; e += 16) {   // this lane: e, e+4, e+8, e+12
        int s0 = cols[e], s1 = cols[e + 4], s2 = cols[e + 8], s3 = cols[e + 12];
        float w0 = nrm[e], w1 = nrm[e + 4], w2 = nrm[e + 8], w3 = nrm[e + 12];
        uint4 u0 = *(const uint4*)(x + (size_t)s0 * DFEAT + sl * 8);
        uint4 u1 = *(const uint4*)(x + (size_t)s1 * DFEAT + sl * 8);
        uint4 u2 = *(const uint4*)(x + (size_t)s2 * DFEAT + sl * 8);
        uint4 u3 = *(const uint4*)(x + (size_t)s3 * DFEAT + sl * 8);
        a0 += w0 * bf16lo(u0.x); a1 += w0 * bf16hi(u0.x);
        a2 += w0 * bf16lo(u0.y); a3 += w0 * bf16hi(u0.y);
        a4 += w0 * bf16lo(u0.z); a5 += w0 * bf16hi(u0.z);
        a6 += w0 * bf16lo(u0.w); a7 += w0 * bf16hi(u0.w);
        a0 += w1 * bf16lo(u1.x); a1 += w1 * bf16hi(u1.x);
        a2 += w1 * bf16lo(u1.y); a3 += w1 * bf16hi(u1.y);
        a4 += w1 * bf16lo(u1.z); a5 += w1 * bf16hi(u1.z);
        a6 += w1 * bf16lo(u1.w); a7 += w1 * bf16hi(u1.w);
        a0 += w2 * bf16lo(u2.x); a1 += w2 * bf16hi(u2.x);
        a2 += w2 * bf16lo(u2.y); a3 += w2 * bf16hi(u2.y);
        a4 += w2 * bf16lo(u2.z); a5 += w2 * bf16hi(u2.z);
        a6 += w2 * bf16lo(u2.w); a7 += w2 * bf16hi(u2.w);
        a0 += w3 * bf16lo(u3.x); a1 += w3 * bf16hi(u3.x);
        a2 += w3 * bf16lo(u3.y); a3 += w3 * bf16hi(u3.y);
        a4 += w3 * bf16lo(u3.z); a5 += w3 * bf16hi(u3.z);
        a6 += w3 * bf16lo(u3.w); a7 += w3 * bf16hi(u3.w);
    }
    for (; e < end; e += 4) {
        int s0 = cols[e];
        float w0 = nrm[e];
        uint4 u0 = *(const uint4*)(x + (size_t)s0 * DFEAT + sl * 8);
        a0 += w0 * bf16lo(u0.x); a1 += w0 * bf16hi(u0.x);
        a2 += w0 * bf16lo(u0.y); a3 += w0 * bf16hi(u0.y);
        a4 += w0 * bf16lo(u0.z); a5 += w0 * bf16hi(u0.z);
        a6 += w0 * bf16lo(u0.w); a7 += w0 * bf16hi(u0.w);
    }
    a0 += __shfl_xor(a0, 16, 64); a0 += __shfl_xor(a0, 32, 64);
    a1 += __shfl_xor(a1, 16, 64); a1 += __shfl_xor(a1, 32, 64);
    a2 += __shfl_xor(a2, 16, 64); a2 += __shfl_xor(a2, 32, 64);
    a3 += __shfl_xor(a3, 16, 64); a3 += __shfl_xor(a3, 32, 64);
    a4 += __shfl_xor(a4, 16, 64); a4 += __shfl_xor(a4, 32, 64);
    a5 += __shfl_xor(a5, 16, 64); a5 += __shfl_xor(a5, 32, 64);
    a6 += __shfl_xor(a6, 16, 64); a6 += __shfl_xor(a6, 32, 64);
    a7 += __shfl_xor(a7, 16, 64); a7 += __shfl_xor(a7, 32, 64);
    if (q == 0) {
        uint4 o;
        o.x = packbf(a0, a1);
        o.y = packbf(a2, a3);
        o.z = packbf(a4, a5);
        o.w = packbf(a6, a7);
        *(uint4*)(y + (size_t)gw * DFEAT + sl * 8) = o;
    }
}

// ---- fc1: 128x128 tile, BK=32 linear LDS, stage-ahead dbuf, XCD swizzle ---
// grid 3128 = 8 XCD chunks x 391; lid = (pid%8)*391 + pid/8
// mode bit0 = RMW accumulate, bit1 = finalize (bias+lrelu+stats)
__global__ __launch_bounds__(256) void fc1_kernel(
    Blk9 blks, const __hip_bfloat16* __restrict__ w1,
    const float* __restrict__ b1, __hip_bfloat16* __restrict__ h1,
    float* __restrict__ gsum, float* __restrict__ gsq,
    int nblk, int kb0, int mode)
{
    __shared__ char smem[33792];   // dbuf: 2 x (A 8K | B 8K); epilogue: 32K tile + 1K stats
    int pid = blockIdx.x;
    int lid = (pid & 7) * 391 + (pid >> 3);   // XCD-chunked bijective remap
    int n0 = (lid & 3) * 128;
    int m0 = (lid >> 2) * 128;
    int tid = threadIdx.x, lane = tid & 63, wv = tid >> 6;
    int wr = wv >> 1, wc = wv & 1;

    f32x4 acc[4][4];
    #pragma unroll
    for (int i = 0; i < 4; ++i)
        #pragma unroll
        for (int j = 0; j < 4; ++j)
            acc[i][j] = (f32x4){0.f, 0.f, 0.f, 0.f};

    int nkt = nblk * 4;

#define STAGE(hb, ktv) do {                                                   \
        const __hip_bfloat16* xp = blks.p[(ktv) >> 2];                        \
        int koff_ = ((ktv) & 3) * 32;                                         \
        int kglob_ = (kb0 + ((ktv) >> 2)) * 128 + koff_;                      \
        char* Ab_ = smem + (hb) * 16384;                                      \
        char* Bb_ = Ab_ + 8192;                                               \
        _Pragma("unroll")                                                     \
        for (int l = 0; l < 2; ++l) {                                         \
            int u = l * 256 + wv * 64 + lane;                                 \
            int row_ = u >> 2, qq_ = u & 3;                                   \
            gload16(xp + (size_t)(m0 + row_) * DFEAT + koff_ + qq_ * 8,       \
                    Ab_ + u * 16);                                            \
            gload16(w1 + (size_t)(n0 + row_) * FAN1 + kglob_ + qq_ * 8,       \
                    Bb_ + u * 16);                                            \
        }                                                                     \
    } while (0)

    STAGE(0, 0);
    for (int kt = 0; kt < nkt; ++kt) {
        int cur = kt & 1;
        __builtin_amdgcn_s_barrier();          // prev compute done; safe to overwrite buf^1
        if (kt + 1 < nkt) {
            STAGE(cur ^ 1, kt + 1);
            asm volatile("s_waitcnt vmcnt(4)" ::: "memory");   // cur's 4 done, next 4 in flight
        } else {
            asm volatile("s_waitcnt vmcnt(0)" ::: "memory");
        }
        __builtin_amdgcn_s_barrier();          // buf[cur] staged for all waves
        char* Ab = smem + cur * 16384;
        char* Bb = Ab + 8192;
        short8 af[4], bfr[4];
        #pragma unroll
        for (int i = 0; i < 4; ++i)
            af[i] = *(const short8*)(Ab + (wr * 64 + i * 16 + (lane & 15)) * 64 + (lane >> 4) * 16);
        #pragma unroll
        for (int j = 0; j < 4; ++j)
            bfr[j] = *(const short8*)(Bb + (wc * 64 + j * 16 + (lane & 15)) * 64 + (lane >> 4) * 16);
        #pragma unroll
        for (int j = 0; j < 4; ++j)
            #pragma unroll
            for (int i = 0; i < 4; ++i)
                acc[i][j] = __builtin_amdgcn_mfma_f32_16x16x32_bf16(af[i], bfr[j], acc[i][j], 0, 0, 0);
    }
#undef STAGE

    // ---- epilogue: LDS transpose, coalesced (RMW) store, optional stats ----
    __syncthreads();
    __hip_bfloat16* tile = (__hip_bfloat16*)smem;      // [128][128]
    float* lsum = (float*)(smem + 32768);              // [128]
    float* lsq  = lsum + 128;
    bool fin = (mode & 2) != 0;
    if (fin && tid < 128) { lsum[tid] = 0.f; lsq[tid] = 0.f; }
    #pragma unroll
    for (int i = 0; i < 4; ++i) {
        #pragma unroll
        for (int j = 0; j < 4; ++j) {
            int col = wc * 64 + j * 16 + (lane & 15);
            #pragma unroll
            for (int r = 0; r < 4; ++r) {
                int row = wr * 64 + i * 16 + (lane >> 4) * 4 + r;
                tile[row * 128 + col] = __float2bfloat16(acc[i][j][r]);
            }
        }
    }
    __syncthreads();

    int cu = tid & 15, tr = tid >> 4;
    float bias[8];
    float s[8], q[8];
    #pragma unroll
    for (int e = 0; e < 8; ++e) { s[e] = 0.f; q[e] = 0.f; }
    if (fin) {
        #pragma unroll
        for (int e = 0; e < 8; ++e) bias[e] = b1[n0 + cu * 8 + e];
    }
    for (int p = 0; p < 8; ++p) {
        int row = p * 16 + tr;
        int gm = m0 + row;
        if (gm >= NNODES) continue;
        short8 fresh = *(const short8*)(tile + row * 128 + cu * 8);
        size_t gidx = (size_t)gm * HIDN + n0 + cu * 8;
        float v[8];
        #pragma unroll
        for (int e = 0; e < 8; ++e) v[e] = bf16s(fresh[e]);
        if (mode & 1) {
            short8 prev = *(const short8*)(h1 + gidx);
            #pragma unroll
            for (int e = 0; e < 8; ++e) v[e] += bf16s(prev[e]);
        }
        if (fin) {
            #pragma unroll
            for (int e = 0; e < 8; ++e) {
                float t = v[e] + bias[e];
                t = (t > 0.f) ? t : 0.2f * t;
                v[e] = t;
                s[e] += t;
                q[e] += t * t;
            }
        }
        short8 outv;
        #pragma unroll
        for (int e = 0; e < 8; ++e) outv[e] = (short)__bfloat16_as_ushort(__float2bfloat16(v[e]));
        *(short8*)(h1 + gidx) = outv;
    }
    if (fin) {
        #pragma unroll
        for (int e = 0; e < 8; ++e) {
            atomicAdd(&lsum[cu * 8 + e], s[e]);
            atomicAdd(&lsq[cu * 8 + e], q[e]);
        }
        __syncthreads();
        if (tid < 128) {
            atomicAdd(&gsum[n0 + tid], lsum[tid]);
            atomicAdd(&gsq[n0 + tid], lsq[tid]);
        }
    }
}

// ---------------- BN finalize: fold into W2 + const vector ----------------
__global__ __launch_bounds__(512) void bn_finalize(
    const float* __restrict__ gsum, const float* __restrict__ gsq,
    const float* __restrict__ gamma, const float* __restrict__ beta,
    const float* __restrict__ w2, const float* __restrict__ b2,
    __hip_bfloat16* __restrict__ w2s, float* __restrict__ cvec)
{
    __shared__ float ts[HIDN];
    int tid = threadIdx.x;              // 512 threads
    float mu = gsum[tid] * (1.0f / NNODES);
    float var = gsq[tid] * (1.0f / NNODES) - mu * mu;
    float s = gamma[tid] * rsqrtf(var + BN_EPS);
    float t = beta[tid] - mu * s;
    ts[tid] = t;
    for (int o = 0; o < OUTD; ++o)
        w2s[o * HIDN + tid] = __float2bfloat16(w2[o * HIDN + tid] * s);
    __syncthreads();
    int lane = tid & 63, wv = tid >> 6; // 8 waves
    for (int o = wv; o < OUTD; o += 8) {
        float p = 0.f;
        for (int j = lane; j < HIDN; j += 64) p += ts[j] * w2[o * HIDN + j];
        #pragma unroll
        for (int off = 32; off; off >>= 1) p += __shfl_xor(p, off, 64);
        if (lane == 0) cvec[o] = p + b2[o];
    }
}

// ---------------- fc2: [N,512]x[512,32] bf16 MFMA ----------------
__global__ __launch_bounds__(256) void fc2_kernel(
    const __hip_bfloat16* __restrict__ h1, const __hip_bfloat16* __restrict__ w2s,
    const float* __restrict__ cvec, float* __restrict__ out)
{
    int gw = (blockIdx.x * 256 + threadIdx.x) >> 6;
    if (gw >= NNODES / 16) return;
    int lane = threadIdx.x & 63;
    int m0 = gw * 16;
    f32x4 acc[2];
    acc[0] = (f32x4){0.f, 0.f, 0.f, 0.f};
    acc[1] = (f32x4){0.f, 0.f, 0.f, 0.f};
    #pragma unroll
    for (int kt = 0; kt < HIDN / 32; ++kt) {
        int k0 = kt * 32;
        short8 a = *(const short8*)(h1 + (size_t)(m0 + (lane & 15)) * HIDN + k0 + (lane >> 4) * 8);
        #pragma unroll
        for (int j = 0; j < 2; ++j) {
            short8 b = *(const short8*)(w2s + (size_t)(j * 16 + (lane & 15)) * HIDN + k0 + (lane >> 4) * 8);
            acc[j] = __builtin_amdgcn_mfma_f32_16x16x32_bf16(a, b, acc[j], 0, 0, 0);
        }
    }
    #pragma unroll
    for (int j = 0; j < 2; ++j) {
        int col = j * 16 + (lane & 15);
        float cadd = cvec[col];
        #pragma unroll
        for (int r = 0; r < 4; ++r) {
            int row = m0 + (lane >> 4) * 4 + r;
            out[(size_t)row * OUTD + col] = acc[j][r] + cadd;
        }
    }
}

// ---------------- host ----------------
struct Ptrs {
    float *deg, *nrm, *gsum, *gsq, *cvec;
    int *cnt, *fillc, *row_ptr, *colsb, *bsum;
    __hip_bfloat16 *slot[9], *h1acc, *w1b, *w2s;
};

static size_t layout(char* base, int nslots, Ptrs& P) {
    char* p = base;
    auto take = [&](size_t b) {
        char* q = (char*)(((uintptr_t)p + 255) & ~(uintptr_t)255);
        p = q + b;
        return q;
    };
    P.deg     = (float*)take((size_t)NNODES * 4);
    P.cnt     = (int*)  take((size_t)NNODES * 4);
    P.fillc   = (int*)  take((size_t)NNODES * 4);
    P.row_ptr = (int*)  take((size_t)(NNODES + 1) * 4);
    P.bsum    = (int*)  take(128 * 4);
    P.colsb   = (int*)  take((size_t)NEDGE * 4);
    P.nrm     = (float*)take((size_t)NEDGE * 4);
    P.h1acc   = (__hip_bfloat16*)take((size_t)NNODES * HIDN * 2);
    P.w1b     = (__hip_bfloat16*)take((size_t)HIDN * FAN1 * 2);
    P.w2s     = (__hip_bfloat16*)take((size_t)OUTD * HIDN * 2);
    P.gsum    = (float*)take(HIDN * 4);
    P.gsq     = (float*)take(HIDN * 4);
    P.cvec    = (float*)take(OUTD * 4);
    for (int i = 0; i < 9; ++i) P.slot[i] = nullptr;
    for (int i = 0; i < nslots; ++i)   // +32KB pad: fc1 A-stage overreads last m-tile
        P.slot[i] = (__hip_bfloat16*)take((size_t)NNODES * DFEAT * 2 + 32768);
    return (size_t)(p - base);
}

extern "C" void kernel_launch(void* const* d_in, const int* in_sizes, int n_in,
                              void* d_out, int out_size, void* d_ws, size_t ws_size,
                              hipStream_t stream)
{
    const float* feature = (const float*)d_in[0];
    const float* coor    = (const float*)d_in[1];
    const float* theta   = (const float*)d_in[2];
    const float* W1      = (const float*)d_in[3];
    const float* b1      = (const float*)d_in[4];
    const float* gamma   = (const float*)d_in[5];
    const float* beta    = (const float*)d_in[6];
    const float* W2      = (const float*)d_in[7];
    const float* b2      = (const float*)d_in[8];
    const int*   ei      = (const int*)d_in[9];
    const int*   mm      = (const int*)d_in[10];
    float* out = (float*)d_out;
    (void)in_sizes; (void)n_in; (void)out_size;

    Ptrs P;
    size_t need9 = layout((char*)0, 9, P);
    size_t need5 = layout((char*)0, 5, P);
    int nslots = (ws_size >= need9) ? 9 : (ws_size >= need5) ? 5 : 3;
    layout((char*)d_ws, nslots, P);

    hipMemsetAsync(P.deg,   0, (size_t)NNODES * 4, stream);
    hipMemsetAsync(P.cnt,   0, (size_t)NNODES * 4, stream);
    hipMemsetAsync(P.fillc, 0, (size_t)NNODES * 4, stream);
    hipMemsetAsync(P.gsum,  0, HIDN * 4, stream);
    hipMemsetAsync(P.gsq,   0, HIDN * 4, stream);

    int eb = (NEDGE + 255) / 256;
    int nchunk = (NNODES + 1023) / 1024;
    edge_kernel<<<eb, 256, 0, stream>>>(ei, coor, theta, mm, P.deg, P.cnt);
    scan_local<<<nchunk, 1024, 0, stream>>>(P.cnt, P.row_ptr, P.bsum, NNODES);
    scan_carry<<<1, 128, 0, stream>>>(P.bsum, nchunk);
    scan_add<<<(NNODES + 255) / 256, 256, 0, stream>>>(P.bsum, P.row_ptr, NNODES);
    fill_kernel<<<eb, 256, 0, stream>>>(ei, coor, theta, mm, P.deg, P.row_ptr,
                                        P.fillc, P.colsb, P.nrm);

    cast_w1_kernel<<<(HIDN * FAN1 + 255) / 256, 256, 0, stream>>>(W1, P.w1b);
    cast_feat_kernel<<<(NNODES * 64) / 256, 256, 0, stream>>>(feature, P.slot[0]);

    int pb = (NNODES * 64) / 256;
    int fgrid = 8 * 391;      // 3128 blocks, XCD-chunk swizzled in-kernel

    auto launch_fc1 = [&](int first_slot, int nblk, int kb0, int mode) {
        Blk9 b;
        for (int i = 0; i < 9; ++i) b.p[i] = P.slot[0];
        for (int i = 0; i < nblk; ++i) b.p[i] = P.slot[(first_slot + i) % nslots];
        fc1_kernel<<<fgrid, 256, 0, stream>>>(b, P.w1b, b1, P.h1acc,
                                              P.gsum, P.gsq, nblk, kb0, mode);
    };

    for (int k = 1; k <= KHOP; ++k) {
        prop_kernel<<<pb, 256, 0, stream>>>(P.slot[(k - 1) % nslots],
                                            P.slot[k % nslots],
                                            P.row_ptr, P.colsb, P.nrm);
        if (nslots == 5 && k == 4) launch_fc1(0, 5, 0, 0);
        if (nslots == 3 && k == 2) launch_fc1(0, 3, 0, 0);
        if (nslots == 3 && k == 5) launch_fc1(0, 3, 3, 1);
    }
    if (nslots == 9) launch_fc1(0, 9, 0, 2);          // single pass, finalize
    if (nslots == 5) launch_fc1(0, 4, 5, 3);          // blocks 5-8 in slots 0-3
    if (nslots == 3) launch_fc1(0, 3, 6, 3);          // blocks 6-8 in slots 0-2

    bn_finalize<<<1, 512, 0, stream>>>(P.gsum, P.gsq, gamma, beta, W2, b2,
                                       P.w2s, P.cvec);
    fc2_kernel<<<(NNODES / 16 * 64 + 255) / 256, 256, 0, stream>>>(P.h1acc, P.w2s,
                                                                   P.cvec, out);
}